// Round 11
// baseline (351.163 us; speedup 1.0000x reference)
//
#include <hip/hip_runtime.h>
#include <hip/hip_bf16.h>

#define S_LEN 2048
#define DMODEL 4096
#define NH 32
#define NKV 8
#define HD 128
#define NQKV 6144
// 1/sqrt(128) * log2(e): scores in log2 domain so v_exp_f32 (=2^x) is the exp
#define ATT_SCALE_L2E 0.1275175213528852f

typedef __bf16 bf16x8 __attribute__((ext_vector_type(8)));
typedef __bf16 bf16x4 __attribute__((ext_vector_type(4)));
typedef float f32x4 __attribute__((ext_vector_type(4)));
typedef float f32x16 __attribute__((ext_vector_type(16)));

// float -> bf16 bits, round-to-nearest-even
__device__ __forceinline__ unsigned short f2b(float f) {
  union { float f; unsigned u; } a; a.f = f;
  unsigned u = a.u;
  return (unsigned short)((u + 0x7FFFu + ((u >> 16) & 1u)) >> 16);
}
// bf16 bits -> float
__device__ __forceinline__ float b2f(unsigned short u) {
  union { unsigned u; float f; } a; a.u = (unsigned)u << 16; return a.f;
}

__device__ __forceinline__ void gl16(const unsigned short* g, unsigned short* l) {
  __builtin_amdgcn_global_load_lds(
      (const __attribute__((address_space(1))) unsigned int*)g,
      (__attribute__((address_space(3))) unsigned int*)l, 16, 0, 0);
}

// ---------------- x fp32 -> bf16 ----------------
__global__ __launch_bounds__(256) void k_cvt_x(const float* __restrict__ x,
                                               unsigned short* __restrict__ xb) {
  int i = blockIdx.x * 256 + threadIdx.x;
  float4 v = ((const float4*)x)[i];
  ushort4 o;
  o.x = f2b(v.x); o.y = f2b(v.y); o.z = f2b(v.z); o.w = f2b(v.w);
  ((ushort4*)xb)[i] = o;
}

// ------------- W (K,N) fp32 -> Wt (N,K) bf16, ushort4 stores -------------
__global__ __launch_bounds__(256) void k_transpose(const float* __restrict__ W,
                                                   unsigned short* __restrict__ Wt,
                                                   int K, int N) {
  __shared__ float tile[64][65];
  int k0 = blockIdx.x * 64, n0 = blockIdx.y * 64;
  int tx = threadIdx.x & 31, ty = threadIdx.x >> 5;
#pragma unroll
  for (int i = 0; i < 8; ++i) {
    int k = ty + i * 8;
    const float* src = W + (size_t)(k0 + k) * N + n0;
    tile[k][tx] = src[tx];
    tile[k][tx + 32] = src[tx + 32];
  }
  __syncthreads();
  int kq = threadIdx.x & 15, nb = threadIdx.x >> 4;
#pragma unroll
  for (int i = 0; i < 4; ++i) {
    int n = nb + i * 16;
    ushort4 o;
    o.x = f2b(tile[kq * 4 + 0][n]);
    o.y = f2b(tile[kq * 4 + 1][n]);
    o.z = f2b(tile[kq * 4 + 2][n]);
    o.w = f2b(tile[kq * 4 + 3][n]);
    *(ushort4*)&Wt[(size_t)(n0 + n) * K + k0 + kq * 4] = o;
  }
}

// ------------- V [S][NKV][HD] bf16 -> V^T [NKV][HD][S] bf16 -------------
__global__ __launch_bounds__(256) void k_vt(const unsigned short* __restrict__ v_bf,
                                            unsigned short* __restrict__ v_t) {
  __shared__ unsigned short tile[64][65];
  int s0 = blockIdx.x * 64, d0 = blockIdx.y * 64, kvh = blockIdx.z;
  int tx = threadIdx.x & 63, ty = threadIdx.x >> 6;
#pragma unroll
  for (int i = 0; i < 16; ++i) {
    int s = ty + i * 4;
    tile[s][tx] = v_bf[((size_t)(s0 + s) * NKV + kvh) * HD + d0 + tx];
  }
  __syncthreads();
#pragma unroll
  for (int i = 0; i < 16; ++i) {
    int d = ty + i * 4;
    v_t[((size_t)kvh * HD + d0 + d) * S_LEN + s0 + tx] = tile[tx][d];
  }
}

// ====== 128 x (TN*64) GEMM, 32x32x16 MFMA, 2 blocks/CU: C = A(MxK)*Bt(NxK), bf16 in ======
// BM=128, BN=TN*64, BK=64; 256 threads = 4 waves (2M x 2N); per-wave output 64 x TN*32
// = 2 x TN tiles of 32x32. Per k16-step: 2 A-reads + TN B-reads feed 2*TN MFMA_32 —
// reads/FLOP 40% lower than the 16x16 version (LDS-read was the binding pipe).
// LDS 32 + TN*16 KB (TN=3: 80 KB, TN=2: 64 KB) -> exactly 2 independent blocks/CU (m114
// overlap). G4 swizzle via pre-swizzled gl16 source + swizzled ds_read col; 8-lane phase
// groups cover all 8 slots -> conflict-free. Boundary vmcnt(4) = stA(t+2)'s 4 instrs.
// A/B operand: lane -> (row = l&31, k-half = l>>5); C/D: col = l&31,
// row = (reg&3) + 8*(reg>>2) + 4*(l>>5)  [m74/m101 HW-verified].
template <int TN, bool BF16OUT>
__global__ __launch_bounds__(256, 2) void k_g128(const unsigned short* __restrict__ A,
                                                 const unsigned short* __restrict__ B,
                                                 void* __restrict__ Cv,
                                                 int M, int N, int K) {
  extern __shared__ __align__(16) unsigned short smem[];
  char* Sc = (char*)smem;
  const int tid = threadIdx.x;
  const int wvid = tid >> 6, l = tid & 63;
  const int wm = wvid >> 1, wn = wvid & 1;
  const int l31 = l & 31, lh = l >> 5;

  // XCD-bijective swizzle (nwg = 512 at both call sites)
  const int cpx = gridDim.x >> 3;
  const int swz = (blockIdx.x & 7) * cpx + (blockIdx.x >> 3);
  const int mtiles = M >> 7;
  const int m0 = (swz % mtiles) * 128;
  const int n0 = (swz / mtiles) * (TN * 64);

  const int NT = K >> 6;

  const int rsw = (l & 7) << 4;
  const int a_row = (wm * 64 + l31) * 128;            // + tm*4096 + col(ks)
  const int b_row = (wn * TN * 32 + l31) * 128;       // + tn*4096 + col(ks)

  // stage: dest chunk c holds rows c*8..c*8+7; lane -> row c*8+(l>>3), pre-swz k8
  const int srow = l >> 3;
  const int st_k8 = (l & 7) ^ (srow & 7);

  auto stA = [&](int tt) {  // 16 KB: 4 gl16/thread (16 chunks / 4 waves)
    if (tt >= NT) return;
    unsigned short* lb = (unsigned short*)(Sc + (tt & 1) * 16384);
#pragma unroll
    for (int j = 0; j < 4; ++j) {
      int c = j * 4 + wvid;
      gl16(A + (size_t)(m0 + c * 8 + srow) * K + tt * 64 + st_k8 * 8, lb + c * 512);
    }
  };
  auto stB = [&](int tt) {  // TN*16 KB: TN*2 gl16/thread
    if (tt >= NT) return;
    unsigned short* lb = (unsigned short*)(Sc + 32768 + (tt & 1) * (TN * 8192));
#pragma unroll
    for (int j = 0; j < TN * 2; ++j) {
      int c = j * 4 + wvid;
      gl16(B + (size_t)(n0 + c * 8 + srow) * K + tt * 64 + st_k8 * 8, lb + c * 512);
    }
  };

  f32x16 acc[2][TN] = {};

  // prologue: t0 fully, t1's A; vmcnt(4) leaves stA(1) in flight
  stA(0); stB(0); stA(1);
  if (NT > 1) asm volatile("s_waitcnt vmcnt(4)" ::: "memory");
  else        asm volatile("s_waitcnt vmcnt(0)" ::: "memory");
  __builtin_amdgcn_s_barrier();

  for (int t = 0; t < NT; ++t) {
    const char* Ab = Sc + (t & 1) * 16384;
    const char* Bb = Sc + 32768 + (t & 1) * (TN * 8192);
    stB(t + 1);  // async into other B buffer
#pragma unroll
    for (int ks = 0; ks < 4; ++ks) {
      const int col = ((ks * 32 + lh * 16)) ^ rsw;
      bf16x8 a[2], b[TN];
#pragma unroll
      for (int tm = 0; tm < 2; ++tm)
        a[tm] = *(const bf16x8*)(Ab + a_row + tm * 4096 + col);
#pragma unroll
      for (int tn = 0; tn < TN; ++tn)
        b[tn] = *(const bf16x8*)(Bb + b_row + tn * 4096 + col);
      __builtin_amdgcn_s_setprio(1);
#pragma unroll
      for (int tm = 0; tm < 2; ++tm)
#pragma unroll
        for (int tn = 0; tn < TN; ++tn)
          acc[tm][tn] = __builtin_amdgcn_mfma_f32_32x32x16_bf16(a[tm], b[tn], acc[tm][tn], 0, 0, 0);
      __builtin_amdgcn_s_setprio(0);
    }
    __builtin_amdgcn_s_barrier();  // all waves done reading buf t
    stA(t + 2);                    // overwrite A buf (t&1) for t+2
    if (t + 1 < NT) {
      if (t + 1 == NT - 1) asm volatile("s_waitcnt vmcnt(0)" ::: "memory");
      else                 asm volatile("s_waitcnt vmcnt(4)" ::: "memory");
      __builtin_amdgcn_s_barrier();
    }
  }

  // epilogue: C/D mapping col=l&31, row=(reg&3)+8*(reg>>2)+4*lh
#pragma unroll
  for (int tm = 0; tm < 2; ++tm) {
    int rowb = m0 + wm * 64 + tm * 32 + 4 * lh;
#pragma unroll
    for (int tn = 0; tn < TN; ++tn) {
      int col = n0 + wn * TN * 32 + tn * 32 + l31;
#pragma unroll
      for (int rg = 0; rg < 4; ++rg)
#pragma unroll
        for (int rr = 0; rr < 4; ++rr) {
          int row = rowb + rg * 8 + rr;
          float v = acc[tm][tn][rg * 4 + rr];
          if constexpr (BF16OUT)
            ((unsigned short*)Cv)[(size_t)row * N + col] = f2b(v);
          else
            ((float*)Cv)[(size_t)row * N + col] = v;
        }
    }
  }
}

// ------------- RoPE + int8 quantize (qkv bf16); dequant scales TRANSPOSED [h][s] -------------
__global__ __launch_bounds__(256) void k_ropequant(const unsigned short* __restrict__ qkv,
                                                   const float* __restrict__ cost,
                                                   const float* __restrict__ sint,
                                                   unsigned short* __restrict__ q_int,
                                                   float* __restrict__ q_ds_t,
                                                   unsigned short* __restrict__ k_int,
                                                   float* __restrict__ k_ds_t,
                                                   unsigned short* __restrict__ v_bf) {
  int s = blockIdx.x;
  int wv = threadIdx.x >> 6, l = threadIdx.x & 63;
  int hh = blockIdx.y * 4 + wv;  // 0..47: [0,32) q, [32,40) k, [40,48) v
  const unsigned short* row = qkv + (size_t)s * NQKV;
  if (hh < NH + NKV) {
    int off = (hh < NH) ? hh * HD : DMODEL + (hh - NH) * HD;
    float t1 = b2f(row[off + l]), t2 = b2f(row[off + 64 + l]);
    float c1 = cost[s * HD + l],      sn1 = sint[s * HD + l];
    float c2 = cost[s * HD + 64 + l], sn2 = sint[s * HD + 64 + l];
    float o1 = t1 * c1 - t2 * sn1;
    float o2 = t2 * c2 + t1 * sn2;
    float amax = fmaxf(fabsf(o1), fabsf(o2));
#pragma unroll
    for (int m = 1; m < 64; m <<= 1) amax = fmaxf(amax, __shfl_xor(amax, m));
    amax = fmaxf(amax, 1e-5f);
    float scale = 127.0f / amax;
    float dscale = amax * (1.0f / 127.0f);
    float v1 = fminf(fmaxf(rintf(o1 * scale), -128.f), 127.f);
    float v2 = fminf(fmaxf(rintf(o2 * scale), -128.f), 127.f);
    if (hh < NH) {
      unsigned short* dst = q_int + ((size_t)s * NH + hh) * HD;
      dst[l] = f2b(v1); dst[l + 64] = f2b(v2);
      if (l == 0) q_ds_t[(size_t)hh * S_LEN + s] = dscale;
    } else {
      int kh = hh - NH;
      unsigned short* dst = k_int + ((size_t)s * NKV + kh) * HD;
      dst[l] = f2b(v1); dst[l + 64] = f2b(v2);
      if (l == 0) k_ds_t[(size_t)kh * S_LEN + s] = dscale;
    }
  } else {
    int vh = hh - (NH + NKV);
    const unsigned short* src = row + DMODEL + NKV * HD + vh * HD;
    unsigned short* dst = v_bf + ((size_t)s * NKV + vh) * HD;
    dst[l] = src[l];
    dst[l + 64] = src[l + 64];
  }
}

// ------------- causal GQA flash attention (round-8 proven): 2 heads/block, swapped QK^T -------------
__global__ __launch_bounds__(256) void k_attn(const unsigned short* __restrict__ q_int,
                                              const float* __restrict__ q_ds_t,
                                              const unsigned short* __restrict__ k_int,
                                              const float* __restrict__ k_ds_t,
                                              const unsigned short* __restrict__ v_t,
                                              unsigned short* __restrict__ o_bf) {
  __shared__ __align__(16) unsigned short K_lds[2][8192];
  __shared__ __align__(16) unsigned short V_lds[2][8192];
  __shared__ __align__(16) unsigned short P_lds[4][16 * 72];

  const int bid = blockIdx.x;
  const int kvh = bid & 7;                    // XCD-pinned K/V
  const int ha = kvh * 4 + ((bid >> 3) & 1) * 2;  // head pair base
  const int qt = 31 - (bid >> 4);             // LPT: longest first
  const int tid = threadIdx.x, wv = tid >> 6, l = tid & 63;
  const int l15 = l & 15, l4 = l >> 4;

  auto stage = [&](int b, int kt) {
    const unsigned short* kB = k_int + (size_t)kt * 64 * (NKV * HD) + kvh * HD;
    const unsigned short* vB = v_t + (size_t)kvh * HD * S_LEN + (size_t)kt * 64;
#pragma unroll
    for (int j = 0; j < 4; ++j) {
      int wi = j * 4 + wv;
      int slot = wi * 64 + l;
      int key = slot >> 4;
      int colb = ((slot & 15) * 16) ^ ((key & 7) << 4);
      gl16(kB + key * (NKV * HD) + (colb >> 1), &K_lds[b][wi * 512]);
      int d = slot >> 3;
      int ckb = ((slot & 7) * 16) ^ ((d & 7) << 4);
      gl16(vB + (size_t)d * S_LEN + (ckb >> 1), &V_lds[b][wi * 512]);
    }
  };

  const int qrow_lo = qt * 64 + wv * 16;
  const int qg = qrow_lo + l15;
  const int crow = qrow_lo + l4 * 4;

  bf16x8 qf[2][4];
  float qsS[2];
#pragma unroll
  for (int h2 = 0; h2 < 2; ++h2) {
    const unsigned short* qp = q_int + ((size_t)(qrow_lo + l15) * NH + ha + h2) * HD + l4 * 8;
#pragma unroll
    for (int kd = 0; kd < 4; ++kd) qf[h2][kd] = *(const bf16x8*)(qp + kd * 32);
    qsS[h2] = ATT_SCALE_L2E * q_ds_t[(size_t)(ha + h2) * S_LEN + qg];
  }

  float m_run[2] = {-3.0e38f, -3.0e38f};
  float l_run[2] = {0.f, 0.f};
  f32x4 o_acc[2][8] = {};

  const int nkt = qt + 1;
  stage(0, 0);
  __syncthreads();

  for (int kt = 0; kt < nkt; ++kt) {
    const int cur = kt & 1;
    f32x4 ksd[4];
    {
      const f32x4* kdp = (const f32x4*)(k_ds_t + (size_t)kvh * S_LEN + kt * 64 + l4 * 4);
#pragma unroll
      for (int nt = 0; nt < 4; ++nt) ksd[nt] = kdp[nt * 4];
    }
    if (kt + 1 < nkt) stage(cur ^ 1, kt + 1);

    f32x4 sacc[2][4] = {};
#pragma unroll
    for (int nt = 0; nt < 4; ++nt) {
      int key = nt * 16 + l15;
#pragma unroll
      for (int kd = 0; kd < 4; ++kd) {
        int byte = key * 256 + kd * 64 + l4 * 16;
        byte ^= (key & 7) << 4;
        bf16x8 kf = *(const bf16x8*)((const char*)&K_lds[cur][0] + byte);
        sacc[0][nt] = __builtin_amdgcn_mfma_f32_16x16x32_bf16(kf, qf[0][kd], sacc[0][nt], 0, 0, 0);
        sacc[1][nt] = __builtin_amdgcn_mfma_f32_16x16x32_bf16(kf, qf[1][kd], sacc[1][nt], 0, 0, 0);
      }
    }

    bf16x8 pa[2][2];
#pragma unroll
    for (int h2 = 0; h2 < 2; ++h2) {
      float p[4][4];
      float tmax = -3.0e38f;
#pragma unroll
      for (int nt = 0; nt < 4; ++nt) {
        int keyb = kt * 64 + nt * 16 + l4 * 4;
#pragma unroll
        for (int r = 0; r < 4; ++r) {
          float sc = sacc[h2][nt][r] * (qsS[h2] * ksd[nt][r]);
          sc = (keyb + r <= qg) ? sc : -3.0e38f;
          p[nt][r] = sc;
          tmax = fmaxf(tmax, sc);
        }
      }
      tmax = fmaxf(tmax, __shfl_xor(tmax, 16));
      tmax = fmaxf(tmax, __shfl_xor(tmax, 32));

      float nm = fmaxf(m_run[h2], tmax);
      bool need = tmax > m_run[h2] + 11.0f;
      if (__ballot(need)) {
        float corr = __builtin_amdgcn_exp2f(m_run[h2] - nm);
        m_run[h2] = nm;
        l_run[h2] *= corr;
        float cq[4];
#pragma unroll
        for (int r = 0; r < 4; ++r) cq[r] = __shfl(corr, (l & 48) | (l4 * 4 + r));
#pragma unroll
        for (int dt = 0; dt < 8; ++dt)
#pragma unroll
          for (int r = 0; r < 4; ++r) o_acc[h2][dt][r] *= cq[r];
      }

      float psum = 0.f;
#pragma unroll
      for (int nt = 0; nt < 4; ++nt)
#pragma unroll
        for (int r = 0; r < 4; ++r) {
          float e = __builtin_amdgcn_exp2f(p[nt][r] - m_run[h2]);
          p[nt][r] = e;
          psum += e;
        }
      psum += __shfl_xor(psum, 16);
      psum += __shfl_xor(psum, 32);
      l_run[h2] += psum;

#pragma unroll
      for (int nt = 0; nt < 4; ++nt) {
        bf16x4 pk;
        pk[0] = (__bf16)p[nt][0]; pk[1] = (__bf16)p[nt][1];
        pk[2] = (__bf16)p[nt][2]; pk[3] = (__bf16)p[nt][3];
        *(bf16x4*)((char*)&P_lds[wv][0] + l15 * 144 + nt * 32 + l4 * 8) = pk;
      }
#pragma unroll
      for (int kc = 0; kc < 2; ++kc)
        pa[h2][kc] = *(const bf16x8*)((const char*)&P_lds[wv][0] + l15 * 144 + kc * 64 + l4 * 16);
    }

#pragma unroll
    for (int dt = 0; dt < 8; ++dt) {
      int d = dt * 16 + l15;
      int swzv = (d & 7) << 4;
#pragma unroll
      for (int kc = 0; kc < 2; ++kc) {
        int byte = d * 128 + ((kc * 64 + l4 * 16) ^ swzv);
        bf16x8 vb = *(const bf16x8*)((const char*)&V_lds[cur][0] + byte);
        o_acc[0][dt] = __builtin_amdgcn_mfma_f32_16x16x32_bf16(pa[0][kc], vb, o_acc[0][dt], 0, 0, 0);
        o_acc[1][dt] = __builtin_amdgcn_mfma_f32_16x16x32_bf16(pa[1][kc], vb, o_acc[1][dt], 0, 0, 0);
      }
    }
    __syncthreads();
  }

#pragma unroll
  for (int h2 = 0; h2 < 2; ++h2) {
    float inv = 1.0f / l_run[h2];
    float invq[4];
#pragma unroll
    for (int r = 0; r < 4; ++r) invq[r] = __shfl(inv, (l & 48) | (l4 * 4 + r));
#pragma unroll
    for (int dt = 0; dt < 8; ++dt)
#pragma unroll
      for (int r = 0; r < 4; ++r)
        o_bf[(size_t)(crow + r) * (NH * HD) + (ha + h2) * HD + dt * 16 + l15] =
            f2b(o_acc[h2][dt][r] * invq[r]);
  }
}

extern "C" void kernel_launch(void* const* d_in, const int* in_sizes, int n_in,
                              void* d_out, int out_size, void* d_ws, size_t ws_size,
                              hipStream_t stream) {
  const float* x    = (const float*)d_in[0];
  const float* Wq   = (const float*)d_in[1];
  const float* Wk   = (const float*)d_in[2];
  const float* Wv   = (const float*)d_in[3];
  const float* Wo   = (const float*)d_in[4];
  const float* cost = (const float*)d_in[5];
  const float* sint = (const float*)d_in[6];
  float* out = (float*)d_out;
  char* ws = (char*)d_ws;

  unsigned short* xb     = (unsigned short*)(ws);                 // 16 MB (dead after gemm1)
  unsigned short* wqkv_t = (unsigned short*)(ws + 16777216);      // 48 MB (dead after gemm1)
  unsigned short* wo_t   = (unsigned short*)(ws + 67108864);      // 32 MB (4096x4096)
  unsigned short* qkv    = (unsigned short*)(ws + 100663296);     // 24 MB bf16 (dead after ropequant)
  unsigned short* q_int  = (unsigned short*)(ws + 150994944);     // 16 MB
  unsigned short* k_int  = (unsigned short*)(ws + 167772160);     // 4 MB
  unsigned short* v_bf   = (unsigned short*)(ws + 171966464);     // 4 MB
  float*          q_ds_t = (float*)(ws + 176160768);              // 256 KB [NH][S]
  float*          k_ds_t = (float*)(ws + 176422912);              // 64 KB  [NKV][S]
  unsigned short* o_bf   = (unsigned short*)(ws + 176488448);     // 16 MB
  unsigned short* v_t    = (unsigned short*)(ws);                 // 4 MB, aliases dead xb

  hipFuncSetAttribute((const void*)k_g128<3, true>,
                      hipFuncAttributeMaxDynamicSharedMemorySize, 81920);
  hipFuncSetAttribute((const void*)k_g128<2, false>,
                      hipFuncAttributeMaxDynamicSharedMemorySize, 65536);

  k_cvt_x<<<(S_LEN * DMODEL / 4) / 256, 256, 0, stream>>>(x, xb);
  k_transpose<<<dim3(64, 64), 256, 0, stream>>>(Wq, wqkv_t, 4096, 4096);
  k_transpose<<<dim3(64, 16), 256, 0, stream>>>(Wk, wqkv_t + (size_t)4096 * 4096, 4096, 1024);
  k_transpose<<<dim3(64, 16), 256, 0, stream>>>(Wv, wqkv_t + (size_t)5120 * 4096, 4096, 1024);
  k_transpose<<<dim3(64, 64), 256, 0, stream>>>(Wo, wo_t, 4096, 4096);
  // QKV proj: 128x192 tiles -> 512 blocks = 2 blocks/CU; 32x32x16 MFMA; bf16 output
  k_g128<3, true><<<dim3(512), 256, 81920, stream>>>(xb, wqkv_t, qkv, 2048, 6144, 4096);
  k_ropequant<<<dim3(2048, 12), 256, 0, stream>>>(qkv, cost, sint, q_int, q_ds_t, k_int, k_ds_t, v_bf);
  k_vt<<<dim3(32, 2, 8), 256, 0, stream>>>(v_bf, v_t);
  // attention: 512 blocks (2 heads each, shared K/V), LPT order
  k_attn<<<dim3(512), 256, 0, stream>>>(q_int, q_ds_t, k_int, k_ds_t, v_t, o_bf);
  // out proj: 128x128 tiles -> 512 blocks = 2 blocks/CU; 32x32x16 MFMA
  k_g128<2, false><<<dim3(512), 256, 65536, stream>>>(o_bf, wo_t, out, 2048, 4096, 4096);
}

// Round 12
// 330.127 us; speedup vs baseline: 1.0637x; 1.0637x over previous
//
#include <hip/hip_runtime.h>
#include <hip/hip_bf16.h>

#define S_LEN 2048
#define DMODEL 4096
#define NH 32
#define NKV 8
#define HD 128
#define NQKV 6144
// 1/sqrt(128) * log2(e): scores in log2 domain so v_exp_f32 (=2^x) is the exp
#define ATT_SCALE_L2E 0.1275175213528852f

typedef __bf16 bf16x8 __attribute__((ext_vector_type(8)));
typedef __bf16 bf16x4 __attribute__((ext_vector_type(4)));
typedef float f32x4 __attribute__((ext_vector_type(4)));

// float -> bf16 bits, round-to-nearest-even
__device__ __forceinline__ unsigned short f2b(float f) {
  union { float f; unsigned u; } a; a.f = f;
  unsigned u = a.u;
  return (unsigned short)((u + 0x7FFFu + ((u >> 16) & 1u)) >> 16);
}
// bf16 bits -> float
__device__ __forceinline__ float b2f(unsigned short u) {
  union { unsigned u; float f; } a; a.u = (unsigned)u << 16; return a.f;
}

__device__ __forceinline__ void gl16(const unsigned short* g, unsigned short* l) {
  __builtin_amdgcn_global_load_lds(
      (const __attribute__((address_space(1))) unsigned int*)g,
      (__attribute__((address_space(3))) unsigned int*)l, 16, 0, 0);
}

// ---------------- x fp32 -> bf16 ----------------
__global__ __launch_bounds__(256) void k_cvt_x(const float* __restrict__ x,
                                               unsigned short* __restrict__ xb) {
  int i = blockIdx.x * 256 + threadIdx.x;
  float4 v = ((const float4*)x)[i];
  ushort4 o;
  o.x = f2b(v.x); o.y = f2b(v.y); o.z = f2b(v.z); o.w = f2b(v.w);
  ((ushort4*)xb)[i] = o;
}

// ------------- W (K,N) fp32 -> Wt (N,K) bf16, ushort4 stores -------------
__global__ __launch_bounds__(256) void k_transpose(const float* __restrict__ W,
                                                   unsigned short* __restrict__ Wt,
                                                   int K, int N) {
  __shared__ float tile[64][65];
  int k0 = blockIdx.x * 64, n0 = blockIdx.y * 64;
  int tx = threadIdx.x & 31, ty = threadIdx.x >> 5;
#pragma unroll
  for (int i = 0; i < 8; ++i) {
    int k = ty + i * 8;
    const float* src = W + (size_t)(k0 + k) * N + n0;
    tile[k][tx] = src[tx];
    tile[k][tx + 32] = src[tx + 32];
  }
  __syncthreads();
  int kq = threadIdx.x & 15, nb = threadIdx.x >> 4;
#pragma unroll
  for (int i = 0; i < 4; ++i) {
    int n = nb + i * 16;
    ushort4 o;
    o.x = f2b(tile[kq * 4 + 0][n]);
    o.y = f2b(tile[kq * 4 + 1][n]);
    o.z = f2b(tile[kq * 4 + 2][n]);
    o.w = f2b(tile[kq * 4 + 3][n]);
    *(ushort4*)&Wt[(size_t)(n0 + n) * K + k0 + kq * 4] = o;
  }
}

// ------------- V [S][NKV][HD] bf16 -> V^T [NKV][HD][S] bf16 -------------
__global__ __launch_bounds__(256) void k_vt(const unsigned short* __restrict__ v_bf,
                                            unsigned short* __restrict__ v_t) {
  __shared__ unsigned short tile[64][65];
  int s0 = blockIdx.x * 64, d0 = blockIdx.y * 64, kvh = blockIdx.z;
  int tx = threadIdx.x & 63, ty = threadIdx.x >> 6;
#pragma unroll
  for (int i = 0; i < 16; ++i) {
    int s = ty + i * 4;
    tile[s][tx] = v_bf[((size_t)(s0 + s) * NKV + kvh) * HD + d0 + tx];
  }
  __syncthreads();
#pragma unroll
  for (int i = 0; i < 16; ++i) {
    int d = ty + i * 4;
    v_t[((size_t)kvh * HD + d0 + d) * S_LEN + s0 + tx] = tile[tx][d];
  }
}

// ============ 128 x (FN*64) GEMM, 2 blocks/CU (round-10 PROVEN): bf16 in ============
// BM=128, BN=FN*64, BK=64, 512 threads = 8 waves (2Mx4N); per-wave output 64 x FN*16.
// LDS (32 + FN*16) KB -> FN=3: 80 KB, FN=2: 64 KB — both exactly 2 blocks/CU.
// Two INDEPENDENT blocks per CU overlap barrier/read phases with MFMA phases (m114).
// G4 swizzle via pre-swizzled gl16 source + swizzled ds_read col. Boundary vmcnt(2).
template <int FN, bool BF16OUT>
__global__ __launch_bounds__(512, 4) void k_g128(const unsigned short* __restrict__ A,
                                                 const unsigned short* __restrict__ B,
                                                 void* __restrict__ Cv,
                                                 int M, int N, int K) {
  extern __shared__ __align__(16) unsigned short smem[];
  char* Sc = (char*)smem;
  const int tid = threadIdx.x;
  const int wvid = tid >> 6, l = tid & 63;
  const int wm = wvid >> 2, wn = wvid & 3;
  const int l15 = l & 15, l4 = l >> 4;

  const int cpx = gridDim.x >> 3;
  const int swz = (blockIdx.x & 7) * cpx + (blockIdx.x >> 3);
  const int mtiles = M >> 7;
  const int m0 = (swz % mtiles) * 128;
  const int n0 = (swz / mtiles) * (FN * 64);

  const int NT = K >> 6;

  const int rsw = (l15 & 7) << 4;
  const int a_base = (wm * 64 + l15) * 128;
  const int b_base = (wn * FN * 16 + l15) * 128;
  const int c0 = (l4 * 16) ^ rsw;
  const int c1 = (64 + l4 * 16) ^ rsw;

  const int srow = l >> 3;
  const int st_k8 = (l & 7) ^ (srow & 7);

  auto stA = [&](int tt) {
    if (tt >= NT) return;
    const unsigned short* g = A + (size_t)(m0 + wvid * 8 + srow) * K + tt * 64 + st_k8 * 8;
    char* lb = Sc + (tt & 1) * 16384 + wvid * 1024;
#pragma unroll
    for (int j = 0; j < 2; ++j)
      gl16(g + (size_t)(j * 64) * K, (unsigned short*)(lb + j * 8192));
  };
  auto stB = [&](int tt) {
    if (tt >= NT) return;
    const unsigned short* g = B + (size_t)(n0 + wvid * 8 + srow) * K + tt * 64 + st_k8 * 8;
    char* lb = Sc + 32768 + (tt & 1) * (FN * 8192) + wvid * 1024;
#pragma unroll
    for (int j = 0; j < FN; ++j)
      gl16(g + (size_t)(j * 64) * K, (unsigned short*)(lb + j * 8192));
  };

  f32x4 acc[4][FN] = {};

  stA(0); stB(0); stA(1);
  if (NT > 1) asm volatile("s_waitcnt vmcnt(2)" ::: "memory");
  else        asm volatile("s_waitcnt vmcnt(0)" ::: "memory");
  __builtin_amdgcn_s_barrier();

  for (int t = 0; t < NT; ++t) {
    const char* Ab = Sc + (t & 1) * 16384;
    const char* Bb = Sc + 32768 + (t & 1) * (FN * 8192);
    stB(t + 1);
    bf16x8 a[4], b[FN];
#pragma unroll
    for (int fm = 0; fm < 4; ++fm) a[fm] = *(const bf16x8*)(Ab + a_base + fm * 2048 + c0);
#pragma unroll
    for (int fn = 0; fn < FN; ++fn) b[fn] = *(const bf16x8*)(Bb + b_base + fn * 2048 + c0);
    __builtin_amdgcn_s_setprio(1);
#pragma unroll
    for (int fm = 0; fm < 4; ++fm)
#pragma unroll
      for (int fn = 0; fn < FN; ++fn)
        acc[fm][fn] = __builtin_amdgcn_mfma_f32_16x16x32_bf16(a[fm], b[fn], acc[fm][fn], 0, 0, 0);
    __builtin_amdgcn_s_setprio(0);
#pragma unroll
    for (int fm = 0; fm < 4; ++fm) a[fm] = *(const bf16x8*)(Ab + a_base + fm * 2048 + c1);
#pragma unroll
    for (int fn = 0; fn < FN; ++fn) b[fn] = *(const bf16x8*)(Bb + b_base + fn * 2048 + c1);
    __builtin_amdgcn_s_setprio(1);
#pragma unroll
    for (int fm = 0; fm < 4; ++fm)
#pragma unroll
      for (int fn = 0; fn < FN; ++fn)
        acc[fm][fn] = __builtin_amdgcn_mfma_f32_16x16x32_bf16(a[fm], b[fn], acc[fm][fn], 0, 0, 0);
    __builtin_amdgcn_s_setprio(0);
    __builtin_amdgcn_s_barrier();
    stA(t + 2);
    if (t + 1 < NT) {
      if (t + 1 == NT - 1) asm volatile("s_waitcnt vmcnt(0)" ::: "memory");
      else                 asm volatile("s_waitcnt vmcnt(2)" ::: "memory");
      __builtin_amdgcn_s_barrier();
    }
  }

#pragma unroll
  for (int fm = 0; fm < 4; ++fm) {
    int row0 = m0 + wm * 64 + fm * 16 + l4 * 4;
#pragma unroll
    for (int fn = 0; fn < FN; ++fn) {
      int col = n0 + wn * FN * 16 + fn * 16 + l15;
#pragma unroll
      for (int r = 0; r < 4; ++r) {
        if constexpr (BF16OUT)
          ((unsigned short*)Cv)[(size_t)(row0 + r) * N + col] = f2b(acc[fm][fn][r]);
        else
          ((float*)Cv)[(size_t)(row0 + r) * N + col] = acc[fm][fn][r];
      }
    }
  }
}

// ------------- RoPE + int8 quantize (qkv bf16); dequant scales TRANSPOSED [h][s] -------------
__global__ __launch_bounds__(256) void k_ropequant(const unsigned short* __restrict__ qkv,
                                                   const float* __restrict__ cost,
                                                   const float* __restrict__ sint,
                                                   unsigned short* __restrict__ q_int,
                                                   float* __restrict__ q_ds_t,
                                                   unsigned short* __restrict__ k_int,
                                                   float* __restrict__ k_ds_t,
                                                   unsigned short* __restrict__ v_bf) {
  int s = blockIdx.x;
  int wv = threadIdx.x >> 6, l = threadIdx.x & 63;
  int hh = blockIdx.y * 4 + wv;
  const unsigned short* row = qkv + (size_t)s * NQKV;
  if (hh < NH + NKV) {
    int off = (hh < NH) ? hh * HD : DMODEL + (hh - NH) * HD;
    float t1 = b2f(row[off + l]), t2 = b2f(row[off + 64 + l]);
    float c1 = cost[s * HD + l],      sn1 = sint[s * HD + l];
    float c2 = cost[s * HD + 64 + l], sn2 = sint[s * HD + 64 + l];
    float o1 = t1 * c1 - t2 * sn1;
    float o2 = t2 * c2 + t1 * sn2;
    float amax = fmaxf(fabsf(o1), fabsf(o2));
#pragma unroll
    for (int m = 1; m < 64; m <<= 1) amax = fmaxf(amax, __shfl_xor(amax, m));
    amax = fmaxf(amax, 1e-5f);
    float scale = 127.0f / amax;
    float dscale = amax * (1.0f / 127.0f);
    float v1 = fminf(fmaxf(rintf(o1 * scale), -128.f), 127.f);
    float v2 = fminf(fmaxf(rintf(o2 * scale), -128.f), 127.f);
    if (hh < NH) {
      unsigned short* dst = q_int + ((size_t)s * NH + hh) * HD;
      dst[l] = f2b(v1); dst[l + 64] = f2b(v2);
      if (l == 0) q_ds_t[(size_t)hh * S_LEN + s] = dscale;
    } else {
      int kh = hh - NH;
      unsigned short* dst = k_int + ((size_t)s * NKV + kh) * HD;
      dst[l] = f2b(v1); dst[l + 64] = f2b(v2);
      if (l == 0) k_ds_t[(size_t)kh * S_LEN + s] = dscale;
    }
  } else {
    int vh = hh - (NH + NKV);
    const unsigned short* src = row + DMODEL + NKV * HD + vh * HD;
    unsigned short* dst = v_bf + ((size_t)s * NKV + vh) * HD;
    dst[l] = src[l];
    dst[l + 64] = src[l + 64];
  }
}

// ------------- causal GQA flash attention: 512 threads, 4 heads x 32 q-rows, 16 waves/CU -------------
// 512 blocks = 8 kvh x 64 qt32 (LPT). 8 waves = (head = wv&3) x (row-half = wv>>2).
// Same round-10 schedule (stage(t+1) async into other buffer; one __syncthreads per tile);
// K dbuf 32K + V dbuf 32K + P (G4-swizzled, no pad) 16K = exactly 80 KB -> 2 blocks/CU.
__global__ __launch_bounds__(512, 4) void k_attn(const unsigned short* __restrict__ q_int,
                                                 const float* __restrict__ q_ds_t,
                                                 const unsigned short* __restrict__ k_int,
                                                 const float* __restrict__ k_ds_t,
                                                 const unsigned short* __restrict__ v_t,
                                                 unsigned short* __restrict__ o_bf) {
  __shared__ __align__(16) unsigned short K_lds[2][8192];
  __shared__ __align__(16) unsigned short V_lds[2][8192];
  __shared__ __align__(16) unsigned short P_lds[8][1024];  // [wave][16q x 64key], G4-swizzled

  const int bid = blockIdx.x;
  const int kvh = bid & 7;               // XCD-pinned K/V
  const int qt = 63 - (bid >> 3);        // 32-row q tile, LPT: longest first
  const int tid = threadIdx.x, wv = tid >> 6, l = tid & 63;
  const int l15 = l & 15, l4 = l >> 4;
  const int h = kvh * 4 + (wv & 3);      // this wave's head
  const int rh = wv >> 2;                // row half

  auto stage = [&](int b, int kt) {
    const unsigned short* kB = k_int + (size_t)kt * 64 * (NKV * HD) + kvh * HD;
    const unsigned short* vB = v_t + (size_t)kvh * HD * S_LEN + (size_t)kt * 64;
#pragma unroll
    for (int j = 0; j < 2; ++j) {
      int wi = j * 8 + wv;
      int slot = wi * 64 + l;
      int key = slot >> 4;
      int colb = ((slot & 15) * 16) ^ ((key & 7) << 4);
      gl16(kB + key * (NKV * HD) + (colb >> 1), &K_lds[b][wi * 512]);
      int d = slot >> 3;
      int ckb = ((slot & 7) * 16) ^ ((d & 7) << 4);
      gl16(vB + (size_t)d * S_LEN + (ckb >> 1), &V_lds[b][wi * 512]);
    }
  };

  const int qrow_lo = qt * 32 + rh * 16;
  const int qg = qrow_lo + l15;          // this lane's softmax row (swapped layout)
  const int crow = qrow_lo + l4 * 4;     // PV output row base

  bf16x8 qf[4];
  {
    const unsigned short* qp = q_int + ((size_t)qg * NH + h) * HD + l4 * 8;
#pragma unroll
    for (int kd = 0; kd < 4; ++kd) qf[kd] = *(const bf16x8*)(qp + kd * 32);
  }
  const float qsS = ATT_SCALE_L2E * q_ds_t[(size_t)h * S_LEN + qg];

  float m_run = -3.0e38f, l_run = 0.f;
  f32x4 o_acc[8] = {};

  const int nkt = (qt >> 1) + 1;
  stage(0, 0);
  __syncthreads();

  const int psw = (l15 & 7) << 4;        // P swizzle bits (G4)
  for (int kt = 0; kt < nkt; ++kt) {
    const int cur = kt & 1;
    f32x4 ksd[4];
    {
      const f32x4* kdp = (const f32x4*)(k_ds_t + (size_t)kvh * S_LEN + kt * 64 + l4 * 4);
#pragma unroll
      for (int nt = 0; nt < 4; ++nt) ksd[nt] = kdp[nt * 4];
    }
    if (kt + 1 < nkt) stage(cur ^ 1, kt + 1);

    // ---- swapped QK^T: mfma(K,Q) -> S[key][q], q on lane axis ----
    f32x4 sacc[4] = {};
#pragma unroll
    for (int nt = 0; nt < 4; ++nt) {
      int key = nt * 16 + l15;
#pragma unroll
      for (int kd = 0; kd < 4; ++kd) {
        int byte = key * 256 + kd * 64 + l4 * 16;
        byte ^= (key & 7) << 4;
        bf16x8 kf = *(const bf16x8*)((const char*)&K_lds[cur][0] + byte);
        sacc[nt] = __builtin_amdgcn_mfma_f32_16x16x32_bf16(kf, qf[kd], sacc[nt], 0, 0, 0);
      }
    }

    // ---- scale + causal mask + online softmax (log2 domain) ----
    float p[4][4];
    float tmax = -3.0e38f;
#pragma unroll
    for (int nt = 0; nt < 4; ++nt) {
      int keyb = kt * 64 + nt * 16 + l4 * 4;
#pragma unroll
      for (int r = 0; r < 4; ++r) {
        float sc = sacc[nt][r] * (qsS * ksd[nt][r]);
        sc = (keyb + r <= qg) ? sc : -3.0e38f;
        p[nt][r] = sc;
        tmax = fmaxf(tmax, sc);
      }
    }
    tmax = fmaxf(tmax, __shfl_xor(tmax, 16));
    tmax = fmaxf(tmax, __shfl_xor(tmax, 32));

    // T13 defer-max (2^11 headroom)
    float nm = fmaxf(m_run, tmax);
    bool need = tmax > m_run + 11.0f;
    if (__ballot(need)) {
      float corr = __builtin_amdgcn_exp2f(m_run - nm);
      m_run = nm;
      l_run *= corr;
      float cq[4];
#pragma unroll
      for (int r = 0; r < 4; ++r) cq[r] = __shfl(corr, (l & 48) | (l4 * 4 + r));
#pragma unroll
      for (int dt = 0; dt < 8; ++dt)
#pragma unroll
        for (int r = 0; r < 4; ++r) o_acc[dt][r] *= cq[r];
    }

    float psum = 0.f;
#pragma unroll
    for (int nt = 0; nt < 4; ++nt)
#pragma unroll
      for (int r = 0; r < 4; ++r) {
        float e = __builtin_amdgcn_exp2f(p[nt][r] - m_run);
        p[nt][r] = e;
        psum += e;
      }
    psum += __shfl_xor(psum, 16);
    psum += __shfl_xor(psum, 32);
    l_run += psum;

    // ---- P -> per-wave LDS (G4-swizzled, stride 128 B) ----
#pragma unroll
    for (int nt = 0; nt < 4; ++nt) {
      bf16x4 pk;
      pk[0] = (__bf16)p[nt][0]; pk[1] = (__bf16)p[nt][1];
      pk[2] = (__bf16)p[nt][2]; pk[3] = (__bf16)p[nt][3];
      int bw = l15 * 128 + ((nt * 32 + l4 * 8) ^ psw);
      *(bf16x4*)((char*)&P_lds[wv][0] + bw) = pk;
    }
    bf16x8 pa[2];
#pragma unroll
    for (int kc = 0; kc < 2; ++kc) {
      int br = l15 * 128 + ((kc * 64 + l4 * 16) ^ psw);
      pa[kc] = *(const bf16x8*)((const char*)&P_lds[wv][0] + br);
    }

    // ---- PV ----
#pragma unroll
    for (int dt = 0; dt < 8; ++dt) {
      int d = dt * 16 + l15;
      int swzv = (d & 7) << 4;
#pragma unroll
      for (int kc = 0; kc < 2; ++kc) {
        int byte = d * 128 + ((kc * 64 + l4 * 16) ^ swzv);
        bf16x8 vb = *(const bf16x8*)((const char*)&V_lds[cur][0] + byte);
        o_acc[dt] = __builtin_amdgcn_mfma_f32_16x16x32_bf16(pa[kc], vb, o_acc[dt], 0, 0, 0);
      }
    }
    __syncthreads();  // next tile staged; orders K/V buffer reuse
  }

  float inv = 1.0f / l_run;
  float invq[4];
#pragma unroll
  for (int r = 0; r < 4; ++r) invq[r] = __shfl(inv, (l & 48) | (l4 * 4 + r));
#pragma unroll
  for (int dt = 0; dt < 8; ++dt)
#pragma unroll
    for (int r = 0; r < 4; ++r)
      o_bf[(size_t)(crow + r) * (NH * HD) + h * HD + dt * 16 + l15] =
          f2b(o_acc[dt][r] * invq[r]);
}

extern "C" void kernel_launch(void* const* d_in, const int* in_sizes, int n_in,
                              void* d_out, int out_size, void* d_ws, size_t ws_size,
                              hipStream_t stream) {
  const float* x    = (const float*)d_in[0];
  const float* Wq   = (const float*)d_in[1];
  const float* Wk   = (const float*)d_in[2];
  const float* Wv   = (const float*)d_in[3];
  const float* Wo   = (const float*)d_in[4];
  const float* cost = (const float*)d_in[5];
  const float* sint = (const float*)d_in[6];
  float* out = (float*)d_out;
  char* ws = (char*)d_ws;

  unsigned short* xb     = (unsigned short*)(ws);                 // 16 MB (dead after gemm1)
  unsigned short* wqkv_t = (unsigned short*)(ws + 16777216);      // 48 MB (dead after gemm1)
  unsigned short* wo_t   = (unsigned short*)(ws + 67108864);      // 32 MB (4096x4096)
  unsigned short* qkv    = (unsigned short*)(ws + 100663296);     // 24 MB bf16 (dead after ropequant)
  unsigned short* q_int  = (unsigned short*)(ws + 150994944);     // 16 MB
  unsigned short* k_int  = (unsigned short*)(ws + 167772160);     // 4 MB
  unsigned short* v_bf   = (unsigned short*)(ws + 171966464);     // 4 MB
  float*          q_ds_t = (float*)(ws + 176160768);              // 256 KB [NH][S]
  float*          k_ds_t = (float*)(ws + 176422912);              // 64 KB  [NKV][S]
  unsigned short* o_bf   = (unsigned short*)(ws + 176488448);     // 16 MB
  unsigned short* v_t    = (unsigned short*)(ws);                 // 4 MB, aliases dead xb

  hipFuncSetAttribute((const void*)k_g128<3, true>,
                      hipFuncAttributeMaxDynamicSharedMemorySize, 81920);
  hipFuncSetAttribute((const void*)k_g128<2, false>,
                      hipFuncAttributeMaxDynamicSharedMemorySize, 65536);

  k_cvt_x<<<(S_LEN * DMODEL / 4) / 256, 256, 0, stream>>>(x, xb);
  k_transpose<<<dim3(64, 64), 256, 0, stream>>>(Wq, wqkv_t, 4096, 4096);
  k_transpose<<<dim3(64, 16), 256, 0, stream>>>(Wk, wqkv_t + (size_t)4096 * 4096, 4096, 1024);
  k_transpose<<<dim3(64, 16), 256, 0, stream>>>(Wv, wqkv_t + (size_t)5120 * 4096, 4096, 1024);
  k_transpose<<<dim3(64, 64), 256, 0, stream>>>(Wo, wo_t, 4096, 4096);
  // QKV proj: 128x192 tiles -> 512 blocks = 2 blocks/CU (round-10 proven); bf16 output
  k_g128<3, true><<<dim3(512), 512, 81920, stream>>>(xb, wqkv_t, qkv, 2048, 6144, 4096);
  k_ropequant<<<dim3(2048, 12), 256, 0, stream>>>(qkv, cost, sint, q_int, q_ds_t, k_int, k_ds_t, v_bf);
  k_vt<<<dim3(32, 2, 8), 256, 0, stream>>>(v_bf, v_t);
  // attention: 512 blocks x 512 threads (4 heads x 32 q-rows each), 16 waves/CU
  k_attn<<<dim3(512), 512, 0, stream>>>(q_int, q_ds_t, k_int, k_ds_t, v_t, o_bf);
  // out proj: 128x128 tiles -> 512 blocks = 2 blocks/CU (round-10 proven)
  k_g128<2, false><<<dim3(512), 512, 65536, stream>>>(o_bf, wo_t, out, 2048, 4096, 4096);
}

// Round 13
// 316.583 us; speedup vs baseline: 1.1092x; 1.0428x over previous
//
#include <hip/hip_runtime.h>
#include <hip/hip_bf16.h>

#define S_LEN 2048
#define DMODEL 4096
#define NH 32
#define NKV 8
#define HD 128
#define NQKV 6144
#define VOFF (DMODEL + NKV * HD)  // v-section offset inside a qkv row
// 1/sqrt(128) * log2(e): scores in log2 domain so v_exp_f32 (=2^x) is the exp
#define ATT_SCALE_L2E 0.1275175213528852f

typedef __bf16 bf16x8 __attribute__((ext_vector_type(8)));
typedef __bf16 bf16x4 __attribute__((ext_vector_type(4)));
typedef float f32x4 __attribute__((ext_vector_type(4)));

// float -> bf16 bits, round-to-nearest-even
__device__ __forceinline__ unsigned short f2b(float f) {
  union { float f; unsigned u; } a; a.f = f;
  unsigned u = a.u;
  return (unsigned short)((u + 0x7FFFu + ((u >> 16) & 1u)) >> 16);
}
// bf16 bits -> float
__device__ __forceinline__ float b2f(unsigned short u) {
  union { unsigned u; float f; } a; a.u = (unsigned)u << 16; return a.f;
}

__device__ __forceinline__ void gl16(const unsigned short* g, unsigned short* l) {
  __builtin_amdgcn_global_load_lds(
      (const __attribute__((address_space(1))) unsigned int*)g,
      (__attribute__((address_space(3))) unsigned int*)l, 16, 0, 0);
}

// ============ merged prep: x fp32->bf16 + 4 weight transposes (one launch) ============
// segments: Wq [0,4096) | Wk [4096,5120) | Wv [5120,6144) | Wo [6144,10240) | cvt_x [10240,18432)
__global__ __launch_bounds__(256) void k_prep(const float* __restrict__ x,
                                              const float* __restrict__ Wq,
                                              const float* __restrict__ Wk,
                                              const float* __restrict__ Wv,
                                              const float* __restrict__ Wo,
                                              unsigned short* __restrict__ xb,
                                              unsigned short* __restrict__ wqkv_t,
                                              unsigned short* __restrict__ wo_t) {
  __shared__ float tile[64][65];
  const int id = blockIdx.x;
  if (id >= 10240) {  // ---- cvt_x: 8192 blocks x 256 thr x float4 ----
    int i = (id - 10240) * 256 + threadIdx.x;
    float4 v = ((const float4*)x)[i];
    ushort4 o;
    o.x = f2b(v.x); o.y = f2b(v.y); o.z = f2b(v.z); o.w = f2b(v.w);
    ((ushort4*)xb)[i] = o;
    return;
  }
  // ---- 64x64 transpose tile: W (K=4096, N) fp32 -> Wt (N, K) bf16 ----
  const float* W;
  unsigned short* Wt;
  int N, bx, by;
  if (id < 4096)      { W = Wq; Wt = wqkv_t;                         N = 4096; bx = id & 63;          by = id >> 6; }
  else if (id < 5120) { W = Wk; Wt = wqkv_t + (size_t)4096 * 4096;   N = 1024; bx = (id - 4096) & 63; by = (id - 4096) >> 6; }
  else if (id < 6144) { W = Wv; Wt = wqkv_t + (size_t)5120 * 4096;   N = 1024; bx = (id - 5120) & 63; by = (id - 5120) >> 6; }
  else                { W = Wo; Wt = wo_t;                           N = 4096; bx = (id - 6144) & 63; by = (id - 6144) >> 6; }
  const int k0 = bx * 64, n0 = by * 64;
  const int tx = threadIdx.x & 31, ty = threadIdx.x >> 5;
#pragma unroll
  for (int i = 0; i < 8; ++i) {
    int k = ty + i * 8;
    const float* src = W + (size_t)(k0 + k) * N + n0;
    tile[k][tx] = src[tx];
    tile[k][tx + 32] = src[tx + 32];
  }
  __syncthreads();
  int kq = threadIdx.x & 15, nb = threadIdx.x >> 4;
#pragma unroll
  for (int i = 0; i < 4; ++i) {
    int n = nb + i * 16;
    ushort4 o;
    o.x = f2b(tile[kq * 4 + 0][n]);
    o.y = f2b(tile[kq * 4 + 1][n]);
    o.z = f2b(tile[kq * 4 + 2][n]);
    o.w = f2b(tile[kq * 4 + 3][n]);
    *(ushort4*)&Wt[(size_t)(n0 + n) * 4096 + k0 + kq * 4] = o;
  }
}

// ------------- V slice of qkv [S][NQKV] bf16 -> V^T [NKV][HD][S] bf16 -------------
__global__ __launch_bounds__(256) void k_vt(const unsigned short* __restrict__ qkv,
                                            unsigned short* __restrict__ v_t) {
  __shared__ unsigned short tile[64][65];
  int s0 = blockIdx.x * 64, d0 = blockIdx.y * 64, kvh = blockIdx.z;
  int tx = threadIdx.x & 63, ty = threadIdx.x >> 6;
#pragma unroll
  for (int i = 0; i < 16; ++i) {
    int s = ty + i * 4;
    tile[s][tx] = qkv[(size_t)(s0 + s) * NQKV + VOFF + kvh * HD + d0 + tx];
  }
  __syncthreads();
#pragma unroll
  for (int i = 0; i < 16; ++i) {
    int d = ty + i * 4;
    v_t[((size_t)kvh * HD + d0 + d) * S_LEN + s0 + tx] = tile[tx][d];
  }
}

// ============ 128 x (FN*64) GEMM, 2 blocks/CU (round-10 PROVEN): bf16 in ============
// BM=128, BN=FN*64, BK=64, 512 threads = 8 waves (2Mx4N); per-wave output 64 x FN*16.
// LDS (32 + FN*16) KB -> FN=3: 80 KB, FN=2: 64 KB — both exactly 2 blocks/CU.
// Two INDEPENDENT blocks per CU overlap barrier/read phases with MFMA phases (m114).
// G4 swizzle via pre-swizzled gl16 source + swizzled ds_read col. Boundary vmcnt(2).
template <int FN, bool BF16OUT>
__global__ __launch_bounds__(512, 4) void k_g128(const unsigned short* __restrict__ A,
                                                 const unsigned short* __restrict__ B,
                                                 void* __restrict__ Cv,
                                                 int M, int N, int K) {
  extern __shared__ __align__(16) unsigned short smem[];
  char* Sc = (char*)smem;
  const int tid = threadIdx.x;
  const int wvid = tid >> 6, l = tid & 63;
  const int wm = wvid >> 2, wn = wvid & 3;
  const int l15 = l & 15, l4 = l >> 4;

  const int cpx = gridDim.x >> 3;
  const int swz = (blockIdx.x & 7) * cpx + (blockIdx.x >> 3);
  const int mtiles = M >> 7;
  const int m0 = (swz % mtiles) * 128;
  const int n0 = (swz / mtiles) * (FN * 64);

  const int NT = K >> 6;

  const int rsw = (l15 & 7) << 4;
  const int a_base = (wm * 64 + l15) * 128;
  const int b_base = (wn * FN * 16 + l15) * 128;
  const int c0 = (l4 * 16) ^ rsw;
  const int c1 = (64 + l4 * 16) ^ rsw;

  const int srow = l >> 3;
  const int st_k8 = (l & 7) ^ (srow & 7);

  auto stA = [&](int tt) {
    if (tt >= NT) return;
    const unsigned short* g = A + (size_t)(m0 + wvid * 8 + srow) * K + tt * 64 + st_k8 * 8;
    char* lb = Sc + (tt & 1) * 16384 + wvid * 1024;
#pragma unroll
    for (int j = 0; j < 2; ++j)
      gl16(g + (size_t)(j * 64) * K, (unsigned short*)(lb + j * 8192));
  };
  auto stB = [&](int tt) {
    if (tt >= NT) return;
    const unsigned short* g = B + (size_t)(n0 + wvid * 8 + srow) * K + tt * 64 + st_k8 * 8;
    char* lb = Sc + 32768 + (tt & 1) * (FN * 8192) + wvid * 1024;
#pragma unroll
    for (int j = 0; j < FN; ++j)
      gl16(g + (size_t)(j * 64) * K, (unsigned short*)(lb + j * 8192));
  };

  f32x4 acc[4][FN] = {};

  stA(0); stB(0); stA(1);
  if (NT > 1) asm volatile("s_waitcnt vmcnt(2)" ::: "memory");
  else        asm volatile("s_waitcnt vmcnt(0)" ::: "memory");
  __builtin_amdgcn_s_barrier();

  for (int t = 0; t < NT; ++t) {
    const char* Ab = Sc + (t & 1) * 16384;
    const char* Bb = Sc + 32768 + (t & 1) * (FN * 8192);
    stB(t + 1);
    bf16x8 a[4], b[FN];
#pragma unroll
    for (int fm = 0; fm < 4; ++fm) a[fm] = *(const bf16x8*)(Ab + a_base + fm * 2048 + c0);
#pragma unroll
    for (int fn = 0; fn < FN; ++fn) b[fn] = *(const bf16x8*)(Bb + b_base + fn * 2048 + c0);
    __builtin_amdgcn_s_setprio(1);
#pragma unroll
    for (int fm = 0; fm < 4; ++fm)
#pragma unroll
      for (int fn = 0; fn < FN; ++fn)
        acc[fm][fn] = __builtin_amdgcn_mfma_f32_16x16x32_bf16(a[fm], b[fn], acc[fm][fn], 0, 0, 0);
    __builtin_amdgcn_s_setprio(0);
#pragma unroll
    for (int fm = 0; fm < 4; ++fm) a[fm] = *(const bf16x8*)(Ab + a_base + fm * 2048 + c1);
#pragma unroll
    for (int fn = 0; fn < FN; ++fn) b[fn] = *(const bf16x8*)(Bb + b_base + fn * 2048 + c1);
    __builtin_amdgcn_s_setprio(1);
#pragma unroll
    for (int fm = 0; fm < 4; ++fm)
#pragma unroll
      for (int fn = 0; fn < FN; ++fn)
        acc[fm][fn] = __builtin_amdgcn_mfma_f32_16x16x32_bf16(a[fm], b[fn], acc[fm][fn], 0, 0, 0);
    __builtin_amdgcn_s_setprio(0);
    __builtin_amdgcn_s_barrier();
    stA(t + 2);
    if (t + 1 < NT) {
      if (t + 1 == NT - 1) asm volatile("s_waitcnt vmcnt(0)" ::: "memory");
      else                 asm volatile("s_waitcnt vmcnt(2)" ::: "memory");
      __builtin_amdgcn_s_barrier();
    }
  }

#pragma unroll
  for (int fm = 0; fm < 4; ++fm) {
    int row0 = m0 + wm * 64 + fm * 16 + l4 * 4;
#pragma unroll
    for (int fn = 0; fn < FN; ++fn) {
      int col = n0 + wn * FN * 16 + fn * 16 + l15;
#pragma unroll
      for (int r = 0; r < 4; ++r) {
        if constexpr (BF16OUT)
          ((unsigned short*)Cv)[(size_t)(row0 + r) * N + col] = f2b(acc[fm][fn][r]);
        else
          ((float*)Cv)[(size_t)(row0 + r) * N + col] = acc[fm][fn][r];
      }
    }
  }
}

// ------------- RoPE + int8 quantize (q,k only; v handled by k_vt); scales TRANSPOSED [h][s] -------------
__global__ __launch_bounds__(256) void k_ropequant(const unsigned short* __restrict__ qkv,
                                                   const float* __restrict__ cost,
                                                   const float* __restrict__ sint,
                                                   unsigned short* __restrict__ q_int,
                                                   float* __restrict__ q_ds_t,
                                                   unsigned short* __restrict__ k_int,
                                                   float* __restrict__ k_ds_t) {
  int s = blockIdx.x;
  int wv = threadIdx.x >> 6, l = threadIdx.x & 63;
  int hh = blockIdx.y * 4 + wv;  // 0..39: [0,32) q, [32,40) k
  const unsigned short* row = qkv + (size_t)s * NQKV;
  int off = (hh < NH) ? hh * HD : DMODEL + (hh - NH) * HD;
  float t1 = b2f(row[off + l]), t2 = b2f(row[off + 64 + l]);
  float c1 = cost[s * HD + l],      sn1 = sint[s * HD + l];
  float c2 = cost[s * HD + 64 + l], sn2 = sint[s * HD + 64 + l];
  float o1 = t1 * c1 - t2 * sn1;
  float o2 = t2 * c2 + t1 * sn2;
  float amax = fmaxf(fabsf(o1), fabsf(o2));
#pragma unroll
  for (int m = 1; m < 64; m <<= 1) amax = fmaxf(amax, __shfl_xor(amax, m));
  amax = fmaxf(amax, 1e-5f);
  float scale = 127.0f / amax;
  float dscale = amax * (1.0f / 127.0f);
  float v1 = fminf(fmaxf(rintf(o1 * scale), -128.f), 127.f);
  float v2 = fminf(fmaxf(rintf(o2 * scale), -128.f), 127.f);
  if (hh < NH) {
    unsigned short* dst = q_int + ((size_t)s * NH + hh) * HD;
    dst[l] = f2b(v1); dst[l + 64] = f2b(v2);
    if (l == 0) q_ds_t[(size_t)hh * S_LEN + s] = dscale;
  } else {
    int kh = hh - NH;
    unsigned short* dst = k_int + ((size_t)s * NKV + kh) * HD;
    dst[l] = f2b(v1); dst[l + 64] = f2b(v2);
    if (l == 0) k_ds_t[(size_t)kh * S_LEN + s] = dscale;
  }
}

// ------------- causal GQA flash attention (round-12): 512 threads, 4 heads x 32 q-rows -------------
__global__ __launch_bounds__(512, 4) void k_attn(const unsigned short* __restrict__ q_int,
                                                 const float* __restrict__ q_ds_t,
                                                 const unsigned short* __restrict__ k_int,
                                                 const float* __restrict__ k_ds_t,
                                                 const unsigned short* __restrict__ v_t,
                                                 unsigned short* __restrict__ o_bf) {
  __shared__ __align__(16) unsigned short K_lds[2][8192];
  __shared__ __align__(16) unsigned short V_lds[2][8192];
  __shared__ __align__(16) unsigned short P_lds[8][1024];  // [wave][16q x 64key], G4-swizzled

  const int bid = blockIdx.x;
  const int kvh = bid & 7;               // XCD-pinned K/V
  const int qt = 63 - (bid >> 3);        // 32-row q tile, LPT: longest first
  const int tid = threadIdx.x, wv = tid >> 6, l = tid & 63;
  const int l15 = l & 15, l4 = l >> 4;
  const int h = kvh * 4 + (wv & 3);      // this wave's head
  const int rh = wv >> 2;                // row half

  auto stage = [&](int b, int kt) {
    const unsigned short* kB = k_int + (size_t)kt * 64 * (NKV * HD) + kvh * HD;
    const unsigned short* vB = v_t + (size_t)kvh * HD * S_LEN + (size_t)kt * 64;
#pragma unroll
    for (int j = 0; j < 2; ++j) {
      int wi = j * 8 + wv;
      int slot = wi * 64 + l;
      int key = slot >> 4;
      int colb = ((slot & 15) * 16) ^ ((key & 7) << 4);
      gl16(kB + key * (NKV * HD) + (colb >> 1), &K_lds[b][wi * 512]);
      int d = slot >> 3;
      int ckb = ((slot & 7) * 16) ^ ((d & 7) << 4);
      gl16(vB + (size_t)d * S_LEN + (ckb >> 1), &V_lds[b][wi * 512]);
    }
  };

  const int qrow_lo = qt * 32 + rh * 16;
  const int qg = qrow_lo + l15;          // this lane's softmax row (swapped layout)
  const int crow = qrow_lo + l4 * 4;     // PV output row base

  bf16x8 qf[4];
  {
    const unsigned short* qp = q_int + ((size_t)qg * NH + h) * HD + l4 * 8;
#pragma unroll
    for (int kd = 0; kd < 4; ++kd) qf[kd] = *(const bf16x8*)(qp + kd * 32);
  }
  const float qsS = ATT_SCALE_L2E * q_ds_t[(size_t)h * S_LEN + qg];

  float m_run = -3.0e38f, l_run = 0.f;
  f32x4 o_acc[8] = {};

  const int nkt = (qt >> 1) + 1;
  stage(0, 0);
  __syncthreads();

  const int psw = (l15 & 7) << 4;        // P swizzle bits (G4)
  for (int kt = 0; kt < nkt; ++kt) {
    const int cur = kt & 1;
    f32x4 ksd[4];
    {
      const f32x4* kdp = (const f32x4*)(k_ds_t + (size_t)kvh * S_LEN + kt * 64 + l4 * 4);
#pragma unroll
      for (int nt = 0; nt < 4; ++nt) ksd[nt] = kdp[nt * 4];
    }
    if (kt + 1 < nkt) stage(cur ^ 1, kt + 1);

    // ---- swapped QK^T: mfma(K,Q) -> S[key][q], q on lane axis ----
    f32x4 sacc[4] = {};
#pragma unroll
    for (int nt = 0; nt < 4; ++nt) {
      int key = nt * 16 + l15;
#pragma unroll
      for (int kd = 0; kd < 4; ++kd) {
        int byte = key * 256 + kd * 64 + l4 * 16;
        byte ^= (key & 7) << 4;
        bf16x8 kf = *(const bf16x8*)((const char*)&K_lds[cur][0] + byte);
        sacc[nt] = __builtin_amdgcn_mfma_f32_16x16x32_bf16(kf, qf[kd], sacc[nt], 0, 0, 0);
      }
    }

    // ---- scale + causal mask + online softmax (log2 domain) ----
    float p[4][4];
    float tmax = -3.0e38f;
#pragma unroll
    for (int nt = 0; nt < 4; ++nt) {
      int keyb = kt * 64 + nt * 16 + l4 * 4;
#pragma unroll
      for (int r = 0; r < 4; ++r) {
        float sc = sacc[nt][r] * (qsS * ksd[nt][r]);
        sc = (keyb + r <= qg) ? sc : -3.0e38f;
        p[nt][r] = sc;
        tmax = fmaxf(tmax, sc);
      }
    }
    tmax = fmaxf(tmax, __shfl_xor(tmax, 16));
    tmax = fmaxf(tmax, __shfl_xor(tmax, 32));

    // T13 defer-max (2^11 headroom)
    float nm = fmaxf(m_run, tmax);
    bool need = tmax > m_run + 11.0f;
    if (__ballot(need)) {
      float corr = __builtin_amdgcn_exp2f(m_run - nm);
      m_run = nm;
      l_run *= corr;
      float cq[4];
#pragma unroll
      for (int r = 0; r < 4; ++r) cq[r] = __shfl(corr, (l & 48) | (l4 * 4 + r));
#pragma unroll
      for (int dt = 0; dt < 8; ++dt)
#pragma unroll
        for (int r = 0; r < 4; ++r) o_acc[dt][r] *= cq[r];
    }

    float psum = 0.f;
#pragma unroll
    for (int nt = 0; nt < 4; ++nt)
#pragma unroll
      for (int r = 0; r < 4; ++r) {
        float e = __builtin_amdgcn_exp2f(p[nt][r] - m_run);
        p[nt][r] = e;
        psum += e;
      }
    psum += __shfl_xor(psum, 16);
    psum += __shfl_xor(psum, 32);
    l_run += psum;

    // ---- P -> per-wave LDS (G4-swizzled, stride 128 B) ----
#pragma unroll
    for (int nt = 0; nt < 4; ++nt) {
      bf16x4 pk;
      pk[0] = (__bf16)p[nt][0]; pk[1] = (__bf16)p[nt][1];
      pk[2] = (__bf16)p[nt][2]; pk[3] = (__bf16)p[nt][3];
      int bw = l15 * 128 + ((nt * 32 + l4 * 8) ^ psw);
      *(bf16x4*)((char*)&P_lds[wv][0] + bw) = pk;
    }
    bf16x8 pa[2];
#pragma unroll
    for (int kc = 0; kc < 2; ++kc) {
      int br = l15 * 128 + ((kc * 64 + l4 * 16) ^ psw);
      pa[kc] = *(const bf16x8*)((const char*)&P_lds[wv][0] + br);
    }

    // ---- PV ----
#pragma unroll
    for (int dt = 0; dt < 8; ++dt) {
      int d = dt * 16 + l15;
      int swzv = (d & 7) << 4;
#pragma unroll
      for (int kc = 0; kc < 2; ++kc) {
        int byte = d * 128 + ((kc * 64 + l4 * 16) ^ swzv);
        bf16x8 vb = *(const bf16x8*)((const char*)&V_lds[cur][0] + byte);
        o_acc[dt] = __builtin_amdgcn_mfma_f32_16x16x32_bf16(pa[kc], vb, o_acc[dt], 0, 0, 0);
      }
    }
    __syncthreads();  // next tile staged; orders K/V buffer reuse
  }

  float inv = 1.0f / l_run;
  float invq[4];
#pragma unroll
  for (int r = 0; r < 4; ++r) invq[r] = __shfl(inv, (l & 48) | (l4 * 4 + r));
#pragma unroll
  for (int dt = 0; dt < 8; ++dt)
#pragma unroll
    for (int r = 0; r < 4; ++r)
      o_bf[(size_t)(crow + r) * (NH * HD) + h * HD + dt * 16 + l15] =
          f2b(o_acc[dt][r] * invq[r]);
}

extern "C" void kernel_launch(void* const* d_in, const int* in_sizes, int n_in,
                              void* d_out, int out_size, void* d_ws, size_t ws_size,
                              hipStream_t stream) {
  const float* x    = (const float*)d_in[0];
  const float* Wq   = (const float*)d_in[1];
  const float* Wk   = (const float*)d_in[2];
  const float* Wv   = (const float*)d_in[3];
  const float* Wo   = (const float*)d_in[4];
  const float* cost = (const float*)d_in[5];
  const float* sint = (const float*)d_in[6];
  float* out = (float*)d_out;
  char* ws = (char*)d_ws;

  unsigned short* xb     = (unsigned short*)(ws);                 // 16 MB (dead after gemm1)
  unsigned short* wqkv_t = (unsigned short*)(ws + 16777216);      // 48 MB (dead after gemm1)
  unsigned short* wo_t   = (unsigned short*)(ws + 67108864);      // 32 MB (4096x4096)
  unsigned short* qkv    = (unsigned short*)(ws + 100663296);     // 24 MB bf16
  unsigned short* q_int  = (unsigned short*)(ws + 150994944);     // 16 MB
  unsigned short* k_int  = (unsigned short*)(ws + 167772160);     // 4 MB
  float*          q_ds_t = (float*)(ws + 176160768);              // 256 KB [NH][S]
  float*          k_ds_t = (float*)(ws + 176422912);              // 64 KB  [NKV][S]
  unsigned short* o_bf   = (unsigned short*)(ws + 176488448);     // 16 MB
  unsigned short* v_t    = (unsigned short*)(ws);                 // 4 MB, aliases dead xb

  hipFuncSetAttribute((const void*)k_g128<3, true>,
                      hipFuncAttributeMaxDynamicSharedMemorySize, 81920);
  hipFuncSetAttribute((const void*)k_g128<2, false>,
                      hipFuncAttributeMaxDynamicSharedMemorySize, 65536);

  // merged prep: cvt_x + Wq/Wk/Wv/Wo transposes in one launch
  k_prep<<<dim3(18432), 256, 0, stream>>>(x, Wq, Wk, Wv, Wo, xb, wqkv_t, wo_t);
  // QKV proj: 128x192 tiles -> 512 blocks = 2 blocks/CU (round-10 proven); bf16 output
  k_g128<3, true><<<dim3(512), 512, 81920, stream>>>(xb, wqkv_t, qkv, 2048, 6144, 4096);
  // RoPE + quant (q,k only) — v handled by k_vt straight from qkv
  k_ropequant<<<dim3(2048, 10), 256, 0, stream>>>(qkv, cost, sint, q_int, q_ds_t, k_int, k_ds_t);
  k_vt<<<dim3(32, 2, 8), 256, 0, stream>>>(qkv, v_t);
  // attention: 512 blocks x 512 threads (4 heads x 32 q-rows each)
  k_attn<<<dim3(512), 512, 0, stream>>>(q_int, q_ds_t, k_int, k_ds_t, v_t, o_bf);
  // out proj: 128x128 tiles -> 512 blocks = 2 blocks/CU (round-10 proven)
  k_g128<2, false><<<dim3(512), 512, 65536, stream>>>(o_bf, wo_t, out, 2048, 4096, 4096);
}

// Round 14
// 314.192 us; speedup vs baseline: 1.1177x; 1.0076x over previous
//
#include <hip/hip_runtime.h>
#include <hip/hip_bf16.h>

#define S_LEN 2048
#define DMODEL 4096
#define NH 32
#define NKV 8
#define HD 128
#define NQKV 6144
#define VOFF (DMODEL + NKV * HD)  // v-section offset inside a qkv row
// 1/sqrt(128) * log2(e): scores in log2 domain so v_exp_f32 (=2^x) is the exp
#define ATT_SCALE_L2E 0.1275175213528852f

typedef __bf16 bf16x8 __attribute__((ext_vector_type(8)));
typedef __bf16 bf16x4 __attribute__((ext_vector_type(4)));
typedef float f32x4 __attribute__((ext_vector_type(4)));

template <bool B> struct BoolC { static constexpr bool value = B; };

// float -> bf16 bits, round-to-nearest-even
__device__ __forceinline__ unsigned short f2b(float f) {
  union { float f; unsigned u; } a; a.f = f;
  unsigned u = a.u;
  return (unsigned short)((u + 0x7FFFu + ((u >> 16) & 1u)) >> 16);
}
// bf16 bits -> float
__device__ __forceinline__ float b2f(unsigned short u) {
  union { unsigned u; float f; } a; a.u = (unsigned)u << 16; return a.f;
}

__device__ __forceinline__ void gl16(const unsigned short* g, unsigned short* l) {
  __builtin_amdgcn_global_load_lds(
      (const __attribute__((address_space(1))) unsigned int*)g,
      (__attribute__((address_space(3))) unsigned int*)l, 16, 0, 0);
}

// ============ merged prep: x fp32->bf16 + 4 weight transposes (one launch) ============
// segments: Wq [0,4096) | Wk [4096,5120) | Wv [5120,6144) | Wo [6144,10240) | cvt_x [10240,18432)
__global__ __launch_bounds__(256) void k_prep(const float* __restrict__ x,
                                              const float* __restrict__ Wq,
                                              const float* __restrict__ Wk,
                                              const float* __restrict__ Wv,
                                              const float* __restrict__ Wo,
                                              unsigned short* __restrict__ xb,
                                              unsigned short* __restrict__ wqkv_t,
                                              unsigned short* __restrict__ wo_t) {
  __shared__ float tile[64][65];
  const int id = blockIdx.x;
  if (id >= 10240) {  // ---- cvt_x: 8192 blocks x 256 thr x float4 ----
    int i = (id - 10240) * 256 + threadIdx.x;
    float4 v = ((const float4*)x)[i];
    ushort4 o;
    o.x = f2b(v.x); o.y = f2b(v.y); o.z = f2b(v.z); o.w = f2b(v.w);
    ((ushort4*)xb)[i] = o;
    return;
  }
  const float* W;
  unsigned short* Wt;
  int N, bx, by;
  if (id < 4096)      { W = Wq; Wt = wqkv_t;                         N = 4096; bx = id & 63;          by = id >> 6; }
  else if (id < 5120) { W = Wk; Wt = wqkv_t + (size_t)4096 * 4096;   N = 1024; bx = (id - 4096) & 63; by = (id - 4096) >> 6; }
  else if (id < 6144) { W = Wv; Wt = wqkv_t + (size_t)5120 * 4096;   N = 1024; bx = (id - 5120) & 63; by = (id - 5120) >> 6; }
  else                { W = Wo; Wt = wo_t;                           N = 4096; bx = (id - 6144) & 63; by = (id - 6144) >> 6; }
  const int k0 = bx * 64, n0 = by * 64;
  const int tx = threadIdx.x & 31, ty = threadIdx.x >> 5;
#pragma unroll
  for (int i = 0; i < 8; ++i) {
    int k = ty + i * 8;
    const float* src = W + (size_t)(k0 + k) * N + n0;
    tile[k][tx] = src[tx];
    tile[k][tx + 32] = src[tx + 32];
  }
  __syncthreads();
  int kq = threadIdx.x & 15, nb = threadIdx.x >> 4;
#pragma unroll
  for (int i = 0; i < 4; ++i) {
    int n = nb + i * 16;
    ushort4 o;
    o.x = f2b(tile[kq * 4 + 0][n]);
    o.y = f2b(tile[kq * 4 + 1][n]);
    o.z = f2b(tile[kq * 4 + 2][n]);
    o.w = f2b(tile[kq * 4 + 3][n]);
    *(ushort4*)&Wt[(size_t)(n0 + n) * 4096 + k0 + kq * 4] = o;
  }
}

// ============ merged post-proj: RoPE+int8 quant (q,k) + V^T transpose (one launch) ============
// segments: rope [0, 20480) (y = id>>11, s = id&2047, hh = y*4+wave) | vt [20480, 20992)
__global__ __launch_bounds__(256) void k_post(const unsigned short* __restrict__ qkv,
                                              const float* __restrict__ cost,
                                              const float* __restrict__ sint,
                                              unsigned short* __restrict__ q_int,
                                              float* __restrict__ q_ds_t,
                                              unsigned short* __restrict__ k_int,
                                              float* __restrict__ k_ds_t,
                                              unsigned short* __restrict__ v_t) {
  __shared__ unsigned short tile[64][65];
  const int id = blockIdx.x;
  if (id < 20480) {
    // ---- RoPE + int8 quantize; dequant scales TRANSPOSED [h][s] ----
    int y = id >> 11, s = id & 2047;
    int wv = threadIdx.x >> 6, l = threadIdx.x & 63;
    int hh = y * 4 + wv;  // 0..39: [0,32) q, [32,40) k
    const unsigned short* row = qkv + (size_t)s * NQKV;
    int off = (hh < NH) ? hh * HD : DMODEL + (hh - NH) * HD;
    float t1 = b2f(row[off + l]), t2 = b2f(row[off + 64 + l]);
    float c1 = cost[s * HD + l],      sn1 = sint[s * HD + l];
    float c2 = cost[s * HD + 64 + l], sn2 = sint[s * HD + 64 + l];
    float o1 = t1 * c1 - t2 * sn1;
    float o2 = t2 * c2 + t1 * sn2;
    float amax = fmaxf(fabsf(o1), fabsf(o2));
#pragma unroll
    for (int m = 1; m < 64; m <<= 1) amax = fmaxf(amax, __shfl_xor(amax, m));
    amax = fmaxf(amax, 1e-5f);
    float scale = 127.0f / amax;
    float dscale = amax * (1.0f / 127.0f);
    float v1 = fminf(fmaxf(rintf(o1 * scale), -128.f), 127.f);
    float v2 = fminf(fmaxf(rintf(o2 * scale), -128.f), 127.f);
    if (hh < NH) {
      unsigned short* dst = q_int + ((size_t)s * NH + hh) * HD;
      dst[l] = f2b(v1); dst[l + 64] = f2b(v2);
      if (l == 0) q_ds_t[(size_t)hh * S_LEN + s] = dscale;
    } else {
      int kh = hh - NH;
      unsigned short* dst = k_int + ((size_t)s * NKV + kh) * HD;
      dst[l] = f2b(v1); dst[l + 64] = f2b(v2);
      if (l == 0) k_ds_t[(size_t)kh * S_LEN + s] = dscale;
    }
    return;
  }
  // ---- V slice of qkv -> V^T [NKV][HD][S] ----
  int vid = id - 20480;
  int s0 = (vid & 31) * 64, d0 = ((vid >> 5) & 1) * 64, kvh = vid >> 6;
  int tx = threadIdx.x & 63, ty = threadIdx.x >> 6;
#pragma unroll
  for (int i = 0; i < 16; ++i) {
    int s = ty + i * 4;
    tile[s][tx] = qkv[(size_t)(s0 + s) * NQKV + VOFF + kvh * HD + d0 + tx];
  }
  __syncthreads();
#pragma unroll
  for (int i = 0; i < 16; ++i) {
    int d = ty + i * 4;
    v_t[((size_t)kvh * HD + d0 + d) * S_LEN + s0 + tx] = tile[tx][d];
  }
}

// ============ 128 x (FN*64) GEMM, 2 blocks/CU (round-10 PROVEN): bf16 in ============
// BM=128, BN=FN*64, BK=64, 512 threads = 8 waves (2Mx4N); per-wave output 64 x FN*16.
// LDS (32 + FN*16) KB -> FN=3: 80 KB, FN=2: 64 KB — both exactly 2 blocks/CU.
// Two INDEPENDENT blocks per CU overlap barrier/read phases with MFMA phases (m114).
// G4 swizzle via pre-swizzled gl16 source + swizzled ds_read col. Boundary vmcnt(2).
template <int FN, bool BF16OUT>
__global__ __launch_bounds__(512, 4) void k_g128(const unsigned short* __restrict__ A,
                                                 const unsigned short* __restrict__ B,
                                                 void* __restrict__ Cv,
                                                 int M, int N, int K) {
  extern __shared__ __align__(16) unsigned short smem[];
  char* Sc = (char*)smem;
  const int tid = threadIdx.x;
  const int wvid = tid >> 6, l = tid & 63;
  const int wm = wvid >> 2, wn = wvid & 3;
  const int l15 = l & 15, l4 = l >> 4;

  const int cpx = gridDim.x >> 3;
  const int swz = (blockIdx.x & 7) * cpx + (blockIdx.x >> 3);
  const int mtiles = M >> 7;
  const int m0 = (swz % mtiles) * 128;
  const int n0 = (swz / mtiles) * (FN * 64);

  const int NT = K >> 6;

  const int rsw = (l15 & 7) << 4;
  const int a_base = (wm * 64 + l15) * 128;
  const int b_base = (wn * FN * 16 + l15) * 128;
  const int c0 = (l4 * 16) ^ rsw;
  const int c1 = (64 + l4 * 16) ^ rsw;

  const int srow = l >> 3;
  const int st_k8 = (l & 7) ^ (srow & 7);

  auto stA = [&](int tt) {
    if (tt >= NT) return;
    const unsigned short* g = A + (size_t)(m0 + wvid * 8 + srow) * K + tt * 64 + st_k8 * 8;
    char* lb = Sc + (tt & 1) * 16384 + wvid * 1024;
#pragma unroll
    for (int j = 0; j < 2; ++j)
      gl16(g + (size_t)(j * 64) * K, (unsigned short*)(lb + j * 8192));
  };
  auto stB = [&](int tt) {
    if (tt >= NT) return;
    const unsigned short* g = B + (size_t)(n0 + wvid * 8 + srow) * K + tt * 64 + st_k8 * 8;
    char* lb = Sc + 32768 + (tt & 1) * (FN * 8192) + wvid * 1024;
#pragma unroll
    for (int j = 0; j < FN; ++j)
      gl16(g + (size_t)(j * 64) * K, (unsigned short*)(lb + j * 8192));
  };

  f32x4 acc[4][FN] = {};

  stA(0); stB(0); stA(1);
  if (NT > 1) asm volatile("s_waitcnt vmcnt(2)" ::: "memory");
  else        asm volatile("s_waitcnt vmcnt(0)" ::: "memory");
  __builtin_amdgcn_s_barrier();

  for (int t = 0; t < NT; ++t) {
    const char* Ab = Sc + (t & 1) * 16384;
    const char* Bb = Sc + 32768 + (t & 1) * (FN * 8192);
    stB(t + 1);
    bf16x8 a[4], b[FN];
#pragma unroll
    for (int fm = 0; fm < 4; ++fm) a[fm] = *(const bf16x8*)(Ab + a_base + fm * 2048 + c0);
#pragma unroll
    for (int fn = 0; fn < FN; ++fn) b[fn] = *(const bf16x8*)(Bb + b_base + fn * 2048 + c0);
    __builtin_amdgcn_s_setprio(1);
#pragma unroll
    for (int fm = 0; fm < 4; ++fm)
#pragma unroll
      for (int fn = 0; fn < FN; ++fn)
        acc[fm][fn] = __builtin_amdgcn_mfma_f32_16x16x32_bf16(a[fm], b[fn], acc[fm][fn], 0, 0, 0);
    __builtin_amdgcn_s_setprio(0);
#pragma unroll
    for (int fm = 0; fm < 4; ++fm) a[fm] = *(const bf16x8*)(Ab + a_base + fm * 2048 + c1);
#pragma unroll
    for (int fn = 0; fn < FN; ++fn) b[fn] = *(const bf16x8*)(Bb + b_base + fn * 2048 + c1);
    __builtin_amdgcn_s_setprio(1);
#pragma unroll
    for (int fm = 0; fm < 4; ++fm)
#pragma unroll
      for (int fn = 0; fn < FN; ++fn)
        acc[fm][fn] = __builtin_amdgcn_mfma_f32_16x16x32_bf16(a[fm], b[fn], acc[fm][fn], 0, 0, 0);
    __builtin_amdgcn_s_setprio(0);
    __builtin_amdgcn_s_barrier();
    stA(t + 2);
    if (t + 1 < NT) {
      if (t + 1 == NT - 1) asm volatile("s_waitcnt vmcnt(0)" ::: "memory");
      else                 asm volatile("s_waitcnt vmcnt(2)" ::: "memory");
      __builtin_amdgcn_s_barrier();
    }
  }

#pragma unroll
  for (int fm = 0; fm < 4; ++fm) {
    int row0 = m0 + wm * 64 + fm * 16 + l4 * 4;
#pragma unroll
    for (int fn = 0; fn < FN; ++fn) {
      int col = n0 + wn * FN * 16 + fn * 16 + l15;
#pragma unroll
      for (int r = 0; r < 4; ++r) {
        if constexpr (BF16OUT)
          ((unsigned short*)Cv)[(size_t)(row0 + r) * N + col] = f2b(acc[fm][fn][r]);
        else
          ((float*)Cv)[(size_t)(row0 + r) * N + col] = acc[fm][fn][r];
      }
    }
  }
}

// ------------- causal GQA flash attention: 512 threads, 4 heads x 32 q-rows -------------
// Mask elision: all KV tiles except the LAST are provably fully unmasked (max key of
// tile kt<=nkt-2 is 32*qt-33 < qg_min=32*qt) -> compile-time MASKED split of tile body.
__global__ __launch_bounds__(512, 4) void k_attn(const unsigned short* __restrict__ q_int,
                                                 const float* __restrict__ q_ds_t,
                                                 const unsigned short* __restrict__ k_int,
                                                 const float* __restrict__ k_ds_t,
                                                 const unsigned short* __restrict__ v_t,
                                                 unsigned short* __restrict__ o_bf) {
  __shared__ __align__(16) unsigned short K_lds[2][8192];
  __shared__ __align__(16) unsigned short V_lds[2][8192];
  __shared__ __align__(16) unsigned short P_lds[8][1024];  // [wave][16q x 64key], G4-swizzled

  const int bid = blockIdx.x;
  const int kvh = bid & 7;               // XCD-pinned K/V
  const int qt = 63 - (bid >> 3);        // 32-row q tile, LPT: longest first
  const int tid = threadIdx.x, wv = tid >> 6, l = tid & 63;
  const int l15 = l & 15, l4 = l >> 4;
  const int h = kvh * 4 + (wv & 3);      // this wave's head
  const int rh = wv >> 2;                // row half

  auto stage = [&](int b, int kt) {
    const unsigned short* kB = k_int + (size_t)kt * 64 * (NKV * HD) + kvh * HD;
    const unsigned short* vB = v_t + (size_t)kvh * HD * S_LEN + (size_t)kt * 64;
#pragma unroll
    for (int j = 0; j < 2; ++j) {
      int wi = j * 8 + wv;
      int slot = wi * 64 + l;
      int key = slot >> 4;
      int colb = ((slot & 15) * 16) ^ ((key & 7) << 4);
      gl16(kB + key * (NKV * HD) + (colb >> 1), &K_lds[b][wi * 512]);
      int d = slot >> 3;
      int ckb = ((slot & 7) * 16) ^ ((d & 7) << 4);
      gl16(vB + (size_t)d * S_LEN + (ckb >> 1), &V_lds[b][wi * 512]);
    }
  };

  const int qrow_lo = qt * 32 + rh * 16;
  const int qg = qrow_lo + l15;          // this lane's softmax row (swapped layout)
  const int crow = qrow_lo + l4 * 4;     // PV output row base

  bf16x8 qf[4];
  {
    const unsigned short* qp = q_int + ((size_t)qg * NH + h) * HD + l4 * 8;
#pragma unroll
    for (int kd = 0; kd < 4; ++kd) qf[kd] = *(const bf16x8*)(qp + kd * 32);
  }
  const float qsS = ATT_SCALE_L2E * q_ds_t[(size_t)h * S_LEN + qg];

  float m_run = -3.0e38f, l_run = 0.f;
  f32x4 o_acc[8] = {};

  const int nkt = (qt >> 1) + 1;
  stage(0, 0);
  __syncthreads();

  const int psw = (l15 & 7) << 4;        // P swizzle bits (G4)

  auto tileBody = [&](auto mc, int kt) {
    constexpr bool MASKED = decltype(mc)::value;
    const int cur = kt & 1;
    f32x4 ksd[4];
    {
      const f32x4* kdp = (const f32x4*)(k_ds_t + (size_t)kvh * S_LEN + kt * 64 + l4 * 4);
#pragma unroll
      for (int nt = 0; nt < 4; ++nt) ksd[nt] = kdp[nt * 4];
    }
    if (kt + 1 < nkt) stage(cur ^ 1, kt + 1);

    // ---- swapped QK^T: mfma(K,Q) -> S[key][q], q on lane axis ----
    f32x4 sacc[4] = {};
#pragma unroll
    for (int nt = 0; nt < 4; ++nt) {
      int key = nt * 16 + l15;
#pragma unroll
      for (int kd = 0; kd < 4; ++kd) {
        int byte = key * 256 + kd * 64 + l4 * 16;
        byte ^= (key & 7) << 4;
        bf16x8 kf = *(const bf16x8*)((const char*)&K_lds[cur][0] + byte);
        sacc[nt] = __builtin_amdgcn_mfma_f32_16x16x32_bf16(kf, qf[kd], sacc[nt], 0, 0, 0);
      }
    }

    // ---- scale (+ causal mask only on last tile) + online softmax (log2 domain) ----
    float p[4][4];
    float tmax = -3.0e38f;
#pragma unroll
    for (int nt = 0; nt < 4; ++nt) {
#pragma unroll
      for (int r = 0; r < 4; ++r) {
        float sc = sacc[nt][r] * (qsS * ksd[nt][r]);
        if constexpr (MASKED) {
          int keyg = kt * 64 + nt * 16 + l4 * 4 + r;
          sc = (keyg <= qg) ? sc : -3.0e38f;
        }
        p[nt][r] = sc;
        tmax = fmaxf(tmax, sc);
      }
    }
    tmax = fmaxf(tmax, __shfl_xor(tmax, 16));
    tmax = fmaxf(tmax, __shfl_xor(tmax, 32));

    // T13 defer-max (2^11 headroom)
    float nm = fmaxf(m_run, tmax);
    bool need = tmax > m_run + 11.0f;
    if (__ballot(need)) {
      float corr = __builtin_amdgcn_exp2f(m_run - nm);
      m_run = nm;
      l_run *= corr;
      float cq[4];
#pragma unroll
      for (int r = 0; r < 4; ++r) cq[r] = __shfl(corr, (l & 48) | (l4 * 4 + r));
#pragma unroll
      for (int dt = 0; dt < 8; ++dt)
#pragma unroll
        for (int r = 0; r < 4; ++r) o_acc[dt][r] *= cq[r];
    }

    float psum = 0.f;
#pragma unroll
    for (int nt = 0; nt < 4; ++nt)
#pragma unroll
      for (int r = 0; r < 4; ++r) {
        float e = __builtin_amdgcn_exp2f(p[nt][r] - m_run);
        p[nt][r] = e;
        psum += e;
      }
    psum += __shfl_xor(psum, 16);
    psum += __shfl_xor(psum, 32);
    l_run += psum;

    // ---- P -> per-wave LDS (G4-swizzled, stride 128 B) ----
#pragma unroll
    for (int nt = 0; nt < 4; ++nt) {
      bf16x4 pk;
      pk[0] = (__bf16)p[nt][0]; pk[1] = (__bf16)p[nt][1];
      pk[2] = (__bf16)p[nt][2]; pk[3] = (__bf16)p[nt][3];
      int bw = l15 * 128 + ((nt * 32 + l4 * 8) ^ psw);
      *(bf16x4*)((char*)&P_lds[wv][0] + bw) = pk;
    }
    bf16x8 pa[2];
#pragma unroll
    for (int kc = 0; kc < 2; ++kc) {
      int br = l15 * 128 + ((kc * 64 + l4 * 16) ^ psw);
      pa[kc] = *(const bf16x8*)((const char*)&P_lds[wv][0] + br);
    }

    // ---- PV ----
#pragma unroll
    for (int dt = 0; dt < 8; ++dt) {
      int d = dt * 16 + l15;
      int swzv = (d & 7) << 4;
#pragma unroll
      for (int kc = 0; kc < 2; ++kc) {
        int byte = d * 128 + ((kc * 64 + l4 * 16) ^ swzv);
        bf16x8 vb = *(const bf16x8*)((const char*)&V_lds[cur][0] + byte);
        o_acc[dt] = __builtin_amdgcn_mfma_f32_16x16x32_bf16(pa[kc], vb, o_acc[dt], 0, 0, 0);
      }
    }
    __syncthreads();  // next tile staged; orders K/V buffer reuse
  };

  for (int kt = 0; kt + 1 < nkt; ++kt) tileBody(BoolC<false>{}, kt);
  tileBody(BoolC<true>{}, nkt - 1);

  float inv = 1.0f / l_run;
  float invq[4];
#pragma unroll
  for (int r = 0; r < 4; ++r) invq[r] = __shfl(inv, (l & 48) | (l4 * 4 + r));
#pragma unroll
  for (int dt = 0; dt < 8; ++dt)
#pragma unroll
    for (int r = 0; r < 4; ++r)
      o_bf[(size_t)(crow + r) * (NH * HD) + h * HD + dt * 16 + l15] =
          f2b(o_acc[dt][r] * invq[r]);
}

extern "C" void kernel_launch(void* const* d_in, const int* in_sizes, int n_in,
                              void* d_out, int out_size, void* d_ws, size_t ws_size,
                              hipStream_t stream) {
  const float* x    = (const float*)d_in[0];
  const float* Wq   = (const float*)d_in[1];
  const float* Wk   = (const float*)d_in[2];
  const float* Wv   = (const float*)d_in[3];
  const float* Wo   = (const float*)d_in[4];
  const float* cost = (const float*)d_in[5];
  const float* sint = (const float*)d_in[6];
  float* out = (float*)d_out;
  char* ws = (char*)d_ws;

  unsigned short* xb     = (unsigned short*)(ws);                 // 16 MB (dead after gemm1)
  unsigned short* wqkv_t = (unsigned short*)(ws + 16777216);      // 48 MB (dead after gemm1)
  unsigned short* wo_t   = (unsigned short*)(ws + 67108864);      // 32 MB (4096x4096)
  unsigned short* qkv    = (unsigned short*)(ws + 100663296);     // 24 MB bf16
  unsigned short* q_int  = (unsigned short*)(ws + 150994944);     // 16 MB
  unsigned short* k_int  = (unsigned short*)(ws + 167772160);     // 4 MB
  float*          q_ds_t = (float*)(ws + 176160768);              // 256 KB [NH][S]
  float*          k_ds_t = (float*)(ws + 176422912);              // 64 KB  [NKV][S]
  unsigned short* o_bf   = (unsigned short*)(ws + 176488448);     // 16 MB
  unsigned short* v_t    = (unsigned short*)(ws);                 // 4 MB, aliases dead xb

  hipFuncSetAttribute((const void*)k_g128<3, true>,
                      hipFuncAttributeMaxDynamicSharedMemorySize, 81920);
  hipFuncSetAttribute((const void*)k_g128<2, false>,
                      hipFuncAttributeMaxDynamicSharedMemorySize, 65536);

  // merged prep: cvt_x + Wq/Wk/Wv/Wo transposes in one launch
  k_prep<<<dim3(18432), 256, 0, stream>>>(x, Wq, Wk, Wv, Wo, xb, wqkv_t, wo_t);
  // QKV proj: 128x192 tiles -> 512 blocks = 2 blocks/CU; bf16 output
  k_g128<3, true><<<dim3(512), 512, 81920, stream>>>(xb, wqkv_t, qkv, 2048, 6144, 4096);
  // merged post: RoPE+quant (q,k) + V^T transpose in one launch
  k_post<<<dim3(20992), 256, 0, stream>>>(qkv, cost, sint, q_int, q_ds_t, k_int, k_ds_t, v_t);
  // attention: 512 blocks x 512 threads (4 heads x 32 q-rows each), mask-elided tiles
  k_attn<<<dim3(512), 512, 0, stream>>>(q_int, q_ds_t, k_int, k_ds_t, v_t, o_bf);
  // out proj: 128x128 tiles -> 512 blocks = 2 blocks/CU
  k_g128<2, false><<<dim3(512), 512, 65536, stream>>>(o_bf, wo_t, out, 2048, 4096, 4096);
}

// Round 15
// 306.458 us; speedup vs baseline: 1.1459x; 1.0252x over previous
//
#include <hip/hip_runtime.h>
#include <hip/hip_bf16.h>

#define S_LEN 2048
#define DMODEL 4096
#define NH 32
#define NKV 8
#define HD 128
#define NQKV 6144
#define VOFF (DMODEL + NKV * HD)  // v-section offset inside a qkv row
// 1/sqrt(128) * log2(e): scores in log2 domain so v_exp_f32 (=2^x) is the exp
#define ATT_SCALE_L2E 0.1275175213528852f

typedef __bf16 bf16x8 __attribute__((ext_vector_type(8)));
typedef __bf16 bf16x4 __attribute__((ext_vector_type(4)));
typedef float f32x4 __attribute__((ext_vector_type(4)));

template <bool B> struct BoolC { static constexpr bool value = B; };

// float -> bf16 bits, round-to-nearest-even
__device__ __forceinline__ unsigned short f2b(float f) {
  union { float f; unsigned u; } a; a.f = f;
  unsigned u = a.u;
  return (unsigned short)((u + 0x7FFFu + ((u >> 16) & 1u)) >> 16);
}
// bf16 bits -> float
__device__ __forceinline__ float b2f(unsigned short u) {
  union { unsigned u; float f; } a; a.u = (unsigned)u << 16; return a.f;
}

__device__ __forceinline__ void gl16(const unsigned short* g, unsigned short* l) {
  __builtin_amdgcn_global_load_lds(
      (const __attribute__((address_space(1))) unsigned int*)g,
      (__attribute__((address_space(3))) unsigned int*)l, 16, 0, 0);
}

// ============ merged prep: x fp32->bf16 + 4 weight transposes (one launch) ============
__global__ __launch_bounds__(256) void k_prep(const float* __restrict__ x,
                                              const float* __restrict__ Wq,
                                              const float* __restrict__ Wk,
                                              const float* __restrict__ Wv,
                                              const float* __restrict__ Wo,
                                              unsigned short* __restrict__ xb,
                                              unsigned short* __restrict__ wqkv_t,
                                              unsigned short* __restrict__ wo_t) {
  __shared__ float tile[64][65];
  const int id = blockIdx.x;
  if (id >= 10240) {  // ---- cvt_x ----
    int i = (id - 10240) * 256 + threadIdx.x;
    float4 v = ((const float4*)x)[i];
    ushort4 o;
    o.x = f2b(v.x); o.y = f2b(v.y); o.z = f2b(v.z); o.w = f2b(v.w);
    ((ushort4*)xb)[i] = o;
    return;
  }
  const float* W;
  unsigned short* Wt;
  int N, bx, by;
  if (id < 4096)      { W = Wq; Wt = wqkv_t;                         N = 4096; bx = id & 63;          by = id >> 6; }
  else if (id < 5120) { W = Wk; Wt = wqkv_t + (size_t)4096 * 4096;   N = 1024; bx = (id - 4096) & 63; by = (id - 4096) >> 6; }
  else if (id < 6144) { W = Wv; Wt = wqkv_t + (size_t)5120 * 4096;   N = 1024; bx = (id - 5120) & 63; by = (id - 5120) >> 6; }
  else                { W = Wo; Wt = wo_t;                           N = 4096; bx = (id - 6144) & 63; by = (id - 6144) >> 6; }
  const int k0 = bx * 64, n0 = by * 64;
  const int tx = threadIdx.x & 31, ty = threadIdx.x >> 5;
#pragma unroll
  for (int i = 0; i < 8; ++i) {
    int k = ty + i * 8;
    const float* src = W + (size_t)(k0 + k) * N + n0;
    tile[k][tx] = src[tx];
    tile[k][tx + 32] = src[tx + 32];
  }
  __syncthreads();
  int kq = threadIdx.x & 15, nb = threadIdx.x >> 4;
#pragma unroll
  for (int i = 0; i < 4; ++i) {
    int n = nb + i * 16;
    ushort4 o;
    o.x = f2b(tile[kq * 4 + 0][n]);
    o.y = f2b(tile[kq * 4 + 1][n]);
    o.z = f2b(tile[kq * 4 + 2][n]);
    o.w = f2b(tile[kq * 4 + 3][n]);
    *(ushort4*)&Wt[(size_t)(n0 + n) * 4096 + k0 + kq * 4] = o;
  }
}

// ============ merged post-proj: RoPE+int8 quant (q,k) + V^T transpose ============
__global__ __launch_bounds__(256) void k_post(const unsigned short* __restrict__ qkv,
                                              const float* __restrict__ cost,
                                              const float* __restrict__ sint,
                                              unsigned short* __restrict__ q_int,
                                              float* __restrict__ q_ds_t,
                                              unsigned short* __restrict__ k_int,
                                              float* __restrict__ k_ds_t,
                                              unsigned short* __restrict__ v_t) {
  __shared__ unsigned short tile[64][65];
  const int id = blockIdx.x;
  if (id < 20480) {
    int y = id >> 11, s = id & 2047;
    int wv = threadIdx.x >> 6, l = threadIdx.x & 63;
    int hh = y * 4 + wv;
    const unsigned short* row = qkv + (size_t)s * NQKV;
    int off = (hh < NH) ? hh * HD : DMODEL + (hh - NH) * HD;
    float t1 = b2f(row[off + l]), t2 = b2f(row[off + 64 + l]);
    float c1 = cost[s * HD + l],      sn1 = sint[s * HD + l];
    float c2 = cost[s * HD + 64 + l], sn2 = sint[s * HD + 64 + l];
    float o1 = t1 * c1 - t2 * sn1;
    float o2 = t2 * c2 + t1 * sn2;
    float amax = fmaxf(fabsf(o1), fabsf(o2));
#pragma unroll
    for (int m = 1; m < 64; m <<= 1) amax = fmaxf(amax, __shfl_xor(amax, m));
    amax = fmaxf(amax, 1e-5f);
    float scale = 127.0f / amax;
    float dscale = amax * (1.0f / 127.0f);
    float v1 = fminf(fmaxf(rintf(o1 * scale), -128.f), 127.f);
    float v2 = fminf(fmaxf(rintf(o2 * scale), -128.f), 127.f);
    if (hh < NH) {
      unsigned short* dst = q_int + ((size_t)s * NH + hh) * HD;
      dst[l] = f2b(v1); dst[l + 64] = f2b(v2);
      if (l == 0) q_ds_t[(size_t)hh * S_LEN + s] = dscale;
    } else {
      int kh = hh - NH;
      unsigned short* dst = k_int + ((size_t)s * NKV + kh) * HD;
      dst[l] = f2b(v1); dst[l + 64] = f2b(v2);
      if (l == 0) k_ds_t[(size_t)kh * S_LEN + s] = dscale;
    }
    return;
  }
  int vid = id - 20480;
  int s0 = (vid & 31) * 64, d0 = ((vid >> 5) & 1) * 64, kvh = vid >> 6;
  int tx = threadIdx.x & 63, ty = threadIdx.x >> 6;
#pragma unroll
  for (int i = 0; i < 16; ++i) {
    int s = ty + i * 4;
    tile[s][tx] = qkv[(size_t)(s0 + s) * NQKV + VOFF + kvh * HD + d0 + tx];
  }
  __syncthreads();
#pragma unroll
  for (int i = 0; i < 16; ++i) {
    int d = ty + i * 4;
    v_t[((size_t)kvh * HD + d0 + d) * S_LEN + s0 + tx] = tile[tx][d];
  }
}

// ============ 128 x 192 GEMM FN=3, 2 blocks/CU (round-10 PROVEN) — QKV proj ============
__global__ __launch_bounds__(512, 4) void k_g128x3(const unsigned short* __restrict__ A,
                                                   const unsigned short* __restrict__ B,
                                                   unsigned short* __restrict__ C,
                                                   int M, int N, int K) {
  constexpr int FN = 3;
  extern __shared__ __align__(16) unsigned short smem[];
  char* Sc = (char*)smem;
  const int tid = threadIdx.x;
  const int wvid = tid >> 6, l = tid & 63;
  const int wm = wvid >> 2, wn = wvid & 3;
  const int l15 = l & 15, l4 = l >> 4;

  const int cpx = gridDim.x >> 3;
  const int swz = (blockIdx.x & 7) * cpx + (blockIdx.x >> 3);
  const int mtiles = M >> 7;
  const int m0 = (swz % mtiles) * 128;
  const int n0 = (swz / mtiles) * (FN * 64);

  const int NT = K >> 6;

  const int rsw = (l15 & 7) << 4;
  const int a_base = (wm * 64 + l15) * 128;
  const int b_base = (wn * FN * 16 + l15) * 128;
  const int c0 = (l4 * 16) ^ rsw;
  const int c1 = (64 + l4 * 16) ^ rsw;

  const int srow = l >> 3;
  const int st_k8 = (l & 7) ^ (srow & 7);

  auto stA = [&](int tt) {
    if (tt >= NT) return;
    const unsigned short* g = A + (size_t)(m0 + wvid * 8 + srow) * K + tt * 64 + st_k8 * 8;
    char* lb = Sc + (tt & 1) * 16384 + wvid * 1024;
#pragma unroll
    for (int j = 0; j < 2; ++j)
      gl16(g + (size_t)(j * 64) * K, (unsigned short*)(lb + j * 8192));
  };
  auto stB = [&](int tt) {
    if (tt >= NT) return;
    const unsigned short* g = B + (size_t)(n0 + wvid * 8 + srow) * K + tt * 64 + st_k8 * 8;
    char* lb = Sc + 32768 + (tt & 1) * (FN * 8192) + wvid * 1024;
#pragma unroll
    for (int j = 0; j < FN; ++j)
      gl16(g + (size_t)(j * 64) * K, (unsigned short*)(lb + j * 8192));
  };

  f32x4 acc[4][FN] = {};

  stA(0); stB(0); stA(1);
  if (NT > 1) asm volatile("s_waitcnt vmcnt(2)" ::: "memory");
  else        asm volatile("s_waitcnt vmcnt(0)" ::: "memory");
  __builtin_amdgcn_s_barrier();

  for (int t = 0; t < NT; ++t) {
    const char* Ab = Sc + (t & 1) * 16384;
    const char* Bb = Sc + 32768 + (t & 1) * (FN * 8192);
    stB(t + 1);
    bf16x8 a[4], b[FN];
#pragma unroll
    for (int fm = 0; fm < 4; ++fm) a[fm] = *(const bf16x8*)(Ab + a_base + fm * 2048 + c0);
#pragma unroll
    for (int fn = 0; fn < FN; ++fn) b[fn] = *(const bf16x8*)(Bb + b_base + fn * 2048 + c0);
    __builtin_amdgcn_s_setprio(1);
#pragma unroll
    for (int fm = 0; fm < 4; ++fm)
#pragma unroll
      for (int fn = 0; fn < FN; ++fn)
        acc[fm][fn] = __builtin_amdgcn_mfma_f32_16x16x32_bf16(a[fm], b[fn], acc[fm][fn], 0, 0, 0);
    __builtin_amdgcn_s_setprio(0);
#pragma unroll
    for (int fm = 0; fm < 4; ++fm) a[fm] = *(const bf16x8*)(Ab + a_base + fm * 2048 + c1);
#pragma unroll
    for (int fn = 0; fn < FN; ++fn) b[fn] = *(const bf16x8*)(Bb + b_base + fn * 2048 + c1);
    __builtin_amdgcn_s_setprio(1);
#pragma unroll
    for (int fm = 0; fm < 4; ++fm)
#pragma unroll
      for (int fn = 0; fn < FN; ++fn)
        acc[fm][fn] = __builtin_amdgcn_mfma_f32_16x16x32_bf16(a[fm], b[fn], acc[fm][fn], 0, 0, 0);
    __builtin_amdgcn_s_setprio(0);
    __builtin_amdgcn_s_barrier();
    stA(t + 2);
    if (t + 1 < NT) {
      if (t + 1 == NT - 1) asm volatile("s_waitcnt vmcnt(0)" ::: "memory");
      else                 asm volatile("s_waitcnt vmcnt(2)" ::: "memory");
      __builtin_amdgcn_s_barrier();
    }
  }

#pragma unroll
  for (int fm = 0; fm < 4; ++fm) {
    int row0 = m0 + wm * 64 + fm * 16 + l4 * 4;
#pragma unroll
    for (int fn = 0; fn < FN; ++fn) {
      int col = n0 + wn * FN * 16 + fn * 16 + l15;
#pragma unroll
      for (int r = 0; r < 4; ++r)
        C[(size_t)(row0 + r) * N + col] = f2b(acc[fm][fn][r]);
    }
  }
}

// ===== 128 x 128 GEMM, K-SPLIT waves (2M x 2N x 2K), per-wave 64x64 — out proj =====
// 8 waves: wm=wvid&1, wn=(wvid>>1)&1, wk=wvid>>2. Each wave owns ks-half wk of a 64x64
// output tile: 4 A + 4 B reads -> 16 MFMA per K-tile (reads/MFMA 0.5 vs 0.75 before;
// block LDS-read floor 2304 -> 1536 cyc/K-tile). LDS 64 KB (A dbuf 32 + B dbuf 32) ->
// 2 blocks/CU. Epilogue: wk=1 waves dump acc via LDS (reuses the 64KB), wk=0 add+store.
__global__ __launch_bounds__(512, 4) void k_gksplit(const unsigned short* __restrict__ A,
                                                    const unsigned short* __restrict__ B,
                                                    float* __restrict__ C,
                                                    int M, int N, int K) {
  extern __shared__ __align__(16) unsigned short smem[];
  char* Sc = (char*)smem;
  const int tid = threadIdx.x;
  const int wvid = tid >> 6, l = tid & 63;
  const int wm = wvid & 1, wn = (wvid >> 1) & 1, wk = wvid >> 2;
  const int l15 = l & 15, l4 = l >> 4;

  const int cpx = gridDim.x >> 3;
  const int swz = (blockIdx.x & 7) * cpx + (blockIdx.x >> 3);
  const int mtiles = M >> 7;
  const int m0 = (swz % mtiles) * 128;
  const int n0 = (swz / mtiles) * 128;

  const int NT = K >> 6;

  const int rsw = (l15 & 7) << 4;
  const int a_base = (wm * 64 + l15) * 128;
  const int b_base = (wn * 64 + l15) * 128;
  const int ck = (wk * 64 + l4 * 16) ^ rsw;   // this wave's ks-half column

  const int srow = l >> 3;
  const int st_k8 = (l & 7) ^ (srow & 7);

  auto stA = [&](int tt) {
    if (tt >= NT) return;
    const unsigned short* g = A + (size_t)(m0 + wvid * 8 + srow) * K + tt * 64 + st_k8 * 8;
    char* lb = Sc + (tt & 1) * 16384 + wvid * 1024;
#pragma unroll
    for (int j = 0; j < 2; ++j)
      gl16(g + (size_t)(j * 64) * K, (unsigned short*)(lb + j * 8192));
  };
  auto stB = [&](int tt) {
    if (tt >= NT) return;
    const unsigned short* g = B + (size_t)(n0 + wvid * 8 + srow) * K + tt * 64 + st_k8 * 8;
    char* lb = Sc + 32768 + (tt & 1) * 16384 + wvid * 1024;
#pragma unroll
    for (int j = 0; j < 2; ++j)
      gl16(g + (size_t)(j * 64) * K, (unsigned short*)(lb + j * 8192));
  };

  f32x4 acc[4][4] = {};

  stA(0); stB(0); stA(1);
  if (NT > 1) asm volatile("s_waitcnt vmcnt(2)" ::: "memory");
  else        asm volatile("s_waitcnt vmcnt(0)" ::: "memory");
  __builtin_amdgcn_s_barrier();

  for (int t = 0; t < NT; ++t) {
    const char* Ab = Sc + (t & 1) * 16384;
    const char* Bb = Sc + 32768 + (t & 1) * 16384;
    stB(t + 1);
    bf16x8 a[4], b[4];
#pragma unroll
    for (int fm = 0; fm < 4; ++fm) a[fm] = *(const bf16x8*)(Ab + a_base + fm * 2048 + ck);
#pragma unroll
    for (int fn = 0; fn < 4; ++fn) b[fn] = *(const bf16x8*)(Bb + b_base + fn * 2048 + ck);
    __builtin_amdgcn_s_setprio(1);
#pragma unroll
    for (int fm = 0; fm < 4; ++fm)
#pragma unroll
      for (int fn = 0; fn < 4; ++fn)
        acc[fm][fn] = __builtin_amdgcn_mfma_f32_16x16x32_bf16(a[fm], b[fn], acc[fm][fn], 0, 0, 0);
    __builtin_amdgcn_s_setprio(0);
    __builtin_amdgcn_s_barrier();
    stA(t + 2);
    if (t + 1 < NT) {
      if (t + 1 == NT - 1) asm volatile("s_waitcnt vmcnt(0)" ::: "memory");
      else                 asm volatile("s_waitcnt vmcnt(2)" ::: "memory");
      __builtin_amdgcn_s_barrier();
    }
  }

  // ---- epilogue: merge the two ks-halves via LDS (reuse A/B space) ----
  char* xch = Sc + (wm * 2 + wn) * 16384;  // 16 KB per (wm,wn) pair
  if (wk == 1) {
#pragma unroll
    for (int fm = 0; fm < 4; ++fm)
#pragma unroll
      for (int fn = 0; fn < 4; ++fn)
        *(f32x4*)(xch + (fm * 4 + fn) * 1024 + l * 16) = acc[fm][fn];
  }
  __syncthreads();
  if (wk == 0) {
#pragma unroll
    for (int fm = 0; fm < 4; ++fm) {
      int row0 = m0 + wm * 64 + fm * 16 + l4 * 4;
#pragma unroll
      for (int fn = 0; fn < 4; ++fn) {
        f32x4 o = *(const f32x4*)(xch + (fm * 4 + fn) * 1024 + l * 16);
        int col = n0 + wn * 64 + fn * 16 + l15;
#pragma unroll
        for (int r = 0; r < 4; ++r)
          C[(size_t)(row0 + r) * N + col] = acc[fm][fn][r] + o[r];
      }
    }
  }
}

// ------------- causal GQA flash attention (round-14 proven) -------------
__global__ __launch_bounds__(512, 4) void k_attn(const unsigned short* __restrict__ q_int,
                                                 const float* __restrict__ q_ds_t,
                                                 const unsigned short* __restrict__ k_int,
                                                 const float* __restrict__ k_ds_t,
                                                 const unsigned short* __restrict__ v_t,
                                                 unsigned short* __restrict__ o_bf) {
  __shared__ __align__(16) unsigned short K_lds[2][8192];
  __shared__ __align__(16) unsigned short V_lds[2][8192];
  __shared__ __align__(16) unsigned short P_lds[8][1024];

  const int bid = blockIdx.x;
  const int kvh = bid & 7;
  const int qt = 63 - (bid >> 3);
  const int tid = threadIdx.x, wv = tid >> 6, l = tid & 63;
  const int l15 = l & 15, l4 = l >> 4;
  const int h = kvh * 4 + (wv & 3);
  const int rh = wv >> 2;

  auto stage = [&](int b, int kt) {
    const unsigned short* kB = k_int + (size_t)kt * 64 * (NKV * HD) + kvh * HD;
    const unsigned short* vB = v_t + (size_t)kvh * HD * S_LEN + (size_t)kt * 64;
#pragma unroll
    for (int j = 0; j < 2; ++j) {
      int wi = j * 8 + wv;
      int slot = wi * 64 + l;
      int key = slot >> 4;
      int colb = ((slot & 15) * 16) ^ ((key & 7) << 4);
      gl16(kB + key * (NKV * HD) + (colb >> 1), &K_lds[b][wi * 512]);
      int d = slot >> 3;
      int ckb = ((slot & 7) * 16) ^ ((d & 7) << 4);
      gl16(vB + (size_t)d * S_LEN + (ckb >> 1), &V_lds[b][wi * 512]);
    }
  };

  const int qrow_lo = qt * 32 + rh * 16;
  const int qg = qrow_lo + l15;
  const int crow = qrow_lo + l4 * 4;

  bf16x8 qf[4];
  {
    const unsigned short* qp = q_int + ((size_t)qg * NH + h) * HD + l4 * 8;
#pragma unroll
    for (int kd = 0; kd < 4; ++kd) qf[kd] = *(const bf16x8*)(qp + kd * 32);
  }
  const float qsS = ATT_SCALE_L2E * q_ds_t[(size_t)h * S_LEN + qg];

  float m_run = -3.0e38f, l_run = 0.f;
  f32x4 o_acc[8] = {};

  const int nkt = (qt >> 1) + 1;
  stage(0, 0);
  __syncthreads();

  const int psw = (l15 & 7) << 4;

  auto tileBody = [&](auto mc, int kt) {
    constexpr bool MASKED = decltype(mc)::value;
    const int cur = kt & 1;
    f32x4 ksd[4];
    {
      const f32x4* kdp = (const f32x4*)(k_ds_t + (size_t)kvh * S_LEN + kt * 64 + l4 * 4);
#pragma unroll
      for (int nt = 0; nt < 4; ++nt) ksd[nt] = kdp[nt * 4];
    }
    if (kt + 1 < nkt) stage(cur ^ 1, kt + 1);

    f32x4 sacc[4] = {};
#pragma unroll
    for (int nt = 0; nt < 4; ++nt) {
      int key = nt * 16 + l15;
#pragma unroll
      for (int kd = 0; kd < 4; ++kd) {
        int byte = key * 256 + kd * 64 + l4 * 16;
        byte ^= (key & 7) << 4;
        bf16x8 kf = *(const bf16x8*)((const char*)&K_lds[cur][0] + byte);
        sacc[nt] = __builtin_amdgcn_mfma_f32_16x16x32_bf16(kf, qf[kd], sacc[nt], 0, 0, 0);
      }
    }

    float p[4][4];
    float tmax = -3.0e38f;
#pragma unroll
    for (int nt = 0; nt < 4; ++nt) {
#pragma unroll
      for (int r = 0; r < 4; ++r) {
        float sc = sacc[nt][r] * (qsS * ksd[nt][r]);
        if constexpr (MASKED) {
          int keyg = kt * 64 + nt * 16 + l4 * 4 + r;
          sc = (keyg <= qg) ? sc : -3.0e38f;
        }
        p[nt][r] = sc;
        tmax = fmaxf(tmax, sc);
      }
    }
    tmax = fmaxf(tmax, __shfl_xor(tmax, 16));
    tmax = fmaxf(tmax, __shfl_xor(tmax, 32));

    float nm = fmaxf(m_run, tmax);
    bool need = tmax > m_run + 11.0f;
    if (__ballot(need)) {
      float corr = __builtin_amdgcn_exp2f(m_run - nm);
      m_run = nm;
      l_run *= corr;
      float cq[4];
#pragma unroll
      for (int r = 0; r < 4; ++r) cq[r] = __shfl(corr, (l & 48) | (l4 * 4 + r));
#pragma unroll
      for (int dt = 0; dt < 8; ++dt)
#pragma unroll
        for (int r = 0; r < 4; ++r) o_acc[dt][r] *= cq[r];
    }

    float psum = 0.f;
#pragma unroll
    for (int nt = 0; nt < 4; ++nt)
#pragma unroll
      for (int r = 0; r < 4; ++r) {
        float e = __builtin_amdgcn_exp2f(p[nt][r] - m_run);
        p[nt][r] = e;
        psum += e;
      }
    psum += __shfl_xor(psum, 16);
    psum += __shfl_xor(psum, 32);
    l_run += psum;

#pragma unroll
    for (int nt = 0; nt < 4; ++nt) {
      bf16x4 pk;
      pk[0] = (__bf16)p[nt][0]; pk[1] = (__bf16)p[nt][1];
      pk[2] = (__bf16)p[nt][2]; pk[3] = (__bf16)p[nt][3];
      int bw = l15 * 128 + ((nt * 32 + l4 * 8) ^ psw);
      *(bf16x4*)((char*)&P_lds[wv][0] + bw) = pk;
    }
    bf16x8 pa[2];
#pragma unroll
    for (int kc = 0; kc < 2; ++kc) {
      int br = l15 * 128 + ((kc * 64 + l4 * 16) ^ psw);
      pa[kc] = *(const bf16x8*)((const char*)&P_lds[wv][0] + br);
    }

#pragma unroll
    for (int dt = 0; dt < 8; ++dt) {
      int d = dt * 16 + l15;
      int swzv = (d & 7) << 4;
#pragma unroll
      for (int kc = 0; kc < 2; ++kc) {
        int byte = d * 128 + ((kc * 64 + l4 * 16) ^ swzv);
        bf16x8 vb = *(const bf16x8*)((const char*)&V_lds[cur][0] + byte);
        o_acc[dt] = __builtin_amdgcn_mfma_f32_16x16x32_bf16(pa[kc], vb, o_acc[dt], 0, 0, 0);
      }
    }
    __syncthreads();
  };

  for (int kt = 0; kt + 1 < nkt; ++kt) tileBody(BoolC<false>{}, kt);
  tileBody(BoolC<true>{}, nkt - 1);

  float inv = 1.0f / l_run;
  float invq[4];
#pragma unroll
  for (int r = 0; r < 4; ++r) invq[r] = __shfl(inv, (l & 48) | (l4 * 4 + r));
#pragma unroll
  for (int dt = 0; dt < 8; ++dt)
#pragma unroll
    for (int r = 0; r < 4; ++r)
      o_bf[(size_t)(crow + r) * (NH * HD) + h * HD + dt * 16 + l15] =
          f2b(o_acc[dt][r] * invq[r]);
}

extern "C" void kernel_launch(void* const* d_in, const int* in_sizes, int n_in,
                              void* d_out, int out_size, void* d_ws, size_t ws_size,
                              hipStream_t stream) {
  const float* x    = (const float*)d_in[0];
  const float* Wq   = (const float*)d_in[1];
  const float* Wk   = (const float*)d_in[2];
  const float* Wv   = (const float*)d_in[3];
  const float* Wo   = (const float*)d_in[4];
  const float* cost = (const float*)d_in[5];
  const float* sint = (const float*)d_in[6];
  float* out = (float*)d_out;
  char* ws = (char*)d_ws;

  unsigned short* xb     = (unsigned short*)(ws);                 // 16 MB (dead after gemm1)
  unsigned short* wqkv_t = (unsigned short*)(ws + 16777216);      // 48 MB (dead after gemm1)
  unsigned short* wo_t   = (unsigned short*)(ws + 67108864);      // 32 MB (4096x4096)
  unsigned short* qkv    = (unsigned short*)(ws + 100663296);     // 24 MB bf16
  unsigned short* q_int  = (unsigned short*)(ws + 150994944);     // 16 MB
  unsigned short* k_int  = (unsigned short*)(ws + 167772160);     // 4 MB
  float*          q_ds_t = (float*)(ws + 176160768);              // 256 KB [NH][S]
  float*          k_ds_t = (float*)(ws + 176422912);              // 64 KB  [NKV][S]
  unsigned short* o_bf   = (unsigned short*)(ws + 176488448);     // 16 MB
  unsigned short* v_t    = (unsigned short*)(ws);                 // 4 MB, aliases dead xb

  hipFuncSetAttribute((const void*)k_g128x3,
                      hipFuncAttributeMaxDynamicSharedMemorySize, 81920);
  hipFuncSetAttribute((const void*)k_gksplit,
                      hipFuncAttributeMaxDynamicSharedMemorySize, 65536);

  // merged prep: cvt_x + Wq/Wk/Wv/Wo transposes in one launch
  k_prep<<<dim3(18432), 256, 0, stream>>>(x, Wq, Wk, Wv, Wo, xb, wqkv_t, wo_t);
  // QKV proj: 128x192 tiles -> 512 blocks = 2 blocks/CU; bf16 output
  k_g128x3<<<dim3(512), 512, 81920, stream>>>(xb, wqkv_t, qkv, 2048, 6144, 4096);
  // merged post: RoPE+quant (q,k) + V^T transpose in one launch
  k_post<<<dim3(20992), 256, 0, stream>>>(qkv, cost, sint, q_int, q_ds_t, k_int, k_ds_t, v_t);
  // attention: 512 blocks x 512 threads (4 heads x 32 q-rows each), mask-elided tiles
  k_attn<<<dim3(512), 512, 0, stream>>>(q_int, q_ds_t, k_int, k_ds_t, v_t, o_bf);
  // out proj: 128x128 tiles, K-split waves (per-wave 64x64) -> 512 blocks = 2 blocks/CU
  k_gksplit<<<dim3(512), 512, 65536, stream>>>(o_bf, wo_t, out, 2048, 4096, 4096);
}